// Round 1
// baseline (2712.305 us; speedup 1.0000x reference)
//
#include <hip/hip_runtime.h>
#include <math.h>

#define BZ 256
#define NN 360
#define NP1 361
#define MROWS (BZ*NN)   // 92160
#define POOLL 252

__device__ __forceinline__ float lrelu(float x){ return x > 0.f ? x : 0.2f*x; }

// ---------------- zero small stats area ----------------
__global__ void k_zero(float* p, int n){
    int i = blockIdx.x*blockDim.x + threadIdx.x;
    if (i < n) p[i] = 0.f;
}

// ---------------- rowsum: one wave per row ----------------
__global__ __launch_bounds__(256)
void k_rowsum(const float* __restrict__ m, float* __restrict__ rowsum){
    int wid = (blockIdx.x*blockDim.x + threadIdx.x) >> 6;
    int lane = threadIdx.x & 63;
    if (wid >= MROWS) return;
    const float* p = m + (size_t)wid*NN;
    float s = 0.f;
    for (int j = lane; j < NN; j += 64) s += p[j];
    #pragma unroll
    for (int off = 32; off; off >>= 1) s += __shfl_down(s, off);
    if (lane == 0) rowsum[wid] = s;
}

// ---------------- big GEMM: Y = lrelu(rowsum[i]*(bn(A)@W) + bias) (+ bn(A) resid), col stats ----------------
// TM=128 TN=64 TK=24, 256 threads (16x16), micro 8x4
template<bool LOADBN, bool RESID>
__global__ __launch_bounds__(256)
void k_gemm_big(const float* __restrict__ A, const float* __restrict__ W,
                const float* __restrict__ bias, const float* __restrict__ rowsum,
                const float* __restrict__ bns, const float* __restrict__ bnh,
                float* __restrict__ Y, float* __restrict__ colsum, float* __restrict__ colsq)
{
    constexpr int TM=128, TN=64, TK=24;
    __shared__ float As[TM][TK+1];
    __shared__ float Bs[TK][TN+1];
    int t = threadIdx.x;
    int ty = t >> 4, tx = t & 15;
    int rowblk = blockIdx.x * TM;
    int colblk = blockIdx.y * TN;

    float acc[8][4];
    #pragma unroll
    for (int i=0;i<8;i++)
        #pragma unroll
        for (int j=0;j<4;j++) acc[i][j]=0.f;

    for (int k0=0; k0<NN; k0+=TK){
        #pragma unroll
        for (int l=0;l<12;l++){            // 128*24 = 3072 = 12*256
            int idx = t + l*256;
            int r = idx / TK, c = idx % TK;
            float v = A[(size_t)(rowblk + r)*NN + (k0 + c)];
            if (LOADBN) v = v * bns[k0+c] + bnh[k0+c];
            As[r][c] = v;
        }
        #pragma unroll
        for (int l=0;l<6;l++){             // 24*64 = 1536 = 6*256
            int idx = t + l*256;
            int r = idx >> 6, c = idx & 63;
            int col = colblk + c;
            Bs[r][c] = (col < NN) ? W[(size_t)(k0 + r)*NN + col] : 0.f;
        }
        __syncthreads();
        #pragma unroll
        for (int kk=0; kk<TK; kk++){
            float a[8], b[4];
            #pragma unroll
            for (int i=0;i<8;i++) a[i] = As[ty*8+i][kk];
            #pragma unroll
            for (int j=0;j<4;j++) b[j] = Bs[kk][tx*4+j];
            #pragma unroll
            for (int i=0;i<8;i++)
                #pragma unroll
                for (int j=0;j<4;j++) acc[i][j] += a[i]*b[j];
        }
        __syncthreads();
    }

    float colpart_s[4] = {0,0,0,0};
    float colpart_q[4] = {0,0,0,0};
    #pragma unroll
    for (int i=0;i<8;i++){
        int r = rowblk + ty*8 + i;
        float rs = rowsum[r];
        #pragma unroll
        for (int j=0;j<4;j++){
            int col = colblk + tx*4 + j;
            if (col < NN){
                float v = lrelu(rs * acc[i][j] + bias[col]);
                if (RESID){
                    float orig = A[(size_t)r*NN + col];
                    v += orig * bns[col] + bnh[col];
                }
                Y[(size_t)r*NN + col] = v;
                colpart_s[j] += v;
                colpart_q[j] += v*v;
            }
        }
    }
    // reduce partial col sums across the 16 ty groups (reuse As as scratch)
    __syncthreads();
    float* red = &As[0][0];
    #pragma unroll
    for (int j=0;j<4;j++) red[ty*64 + tx*4 + j] = colpart_s[j];
    __syncthreads();
    if (ty == 0){
        #pragma unroll
        for (int j=0;j<4;j++){
            int col = colblk + tx*4 + j;
            if (col < NN){
                float s=0.f;
                for (int g=0; g<16; g++) s += red[g*64 + tx*4 + j];
                atomicAdd(&colsum[col], s);
            }
        }
    }
    __syncthreads();
    #pragma unroll
    for (int j=0;j<4;j++) red[ty*64 + tx*4 + j] = colpart_q[j];
    __syncthreads();
    if (ty == 0){
        #pragma unroll
        for (int j=0;j<4;j++){
            int col = colblk + tx*4 + j;
            if (col < NN){
                float s=0.f;
                for (int g=0; g<16; g++) s += red[g*64 + tx*4 + j];
                atomicAdd(&colsq[col], s);
            }
        }
    }
}

// ---------------- BN finalize: scale/shift per column ----------------
__global__ void k_bnfin(const float* __restrict__ colsum, const float* __restrict__ colsq,
                        const float* __restrict__ g, const float* __restrict__ b, int ncols,
                        float* __restrict__ scale, float* __restrict__ shift){
    int j = blockIdx.x*blockDim.x + threadIdx.x;
    if (j >= ncols) return;
    float mu = colsum[j] / (float)MROWS;
    float var = colsq[j] / (float)MROWS - mu*mu;
    float sc = g[j] * rsqrtf(var + 1e-5f);
    scale[j] = sc;
    shift[j] = b[j] - mu*sc;
}

// ---------------- GEMM2: h1 = lrelu(rs*(bn1(y1)@w1)+b1), sc = lrelu(bn1(y1)@scw + scb) ----------------
// TM=64 TN=80 TK=24, 256 threads, micro 4x5
__global__ __launch_bounds__(256)
void k_gemm2(const float* __restrict__ A, const float* __restrict__ W1,
             const float* __restrict__ SCW, const float* __restrict__ b1,
             const float* __restrict__ scb, const float* __restrict__ rowsum,
             const float* __restrict__ bns, const float* __restrict__ bnh,
             float* __restrict__ h1buf, float* __restrict__ scbuf)
{
    constexpr int TM=64, TN=80, TK=24;
    __shared__ float As[TM][TK+1];
    __shared__ float Bs[TK][TN+1];
    int t = threadIdx.x;
    int ty = t >> 4, tx = t & 15;
    int rowblk = blockIdx.x * TM;
    float acc[4][5];
    #pragma unroll
    for (int i=0;i<4;i++)
        #pragma unroll
        for (int j=0;j<5;j++) acc[i][j]=0.f;

    for (int k0=0;k0<NN;k0+=TK){
        #pragma unroll
        for (int l=0;l<6;l++){             // 64*24 = 1536
            int idx = t + l*256;
            int r = idx / TK, c = idx % TK;
            As[r][c] = A[(size_t)(rowblk+r)*NN + k0 + c]*bns[k0+c] + bnh[k0+c];
        }
        #pragma unroll
        for (int l=0;l<8;l++){             // 24*80 = 1920 < 2048
            int idx = t + l*256;
            if (idx < TK*TN){
                int r = idx / TN, c = idx % TN;
                Bs[r][c] = (c < 64) ? W1[(size_t)(k0+r)*64 + c] : SCW[(size_t)(k0+r)*16 + (c-64)];
            }
        }
        __syncthreads();
        #pragma unroll
        for (int kk=0;kk<TK;kk++){
            float a[4], bb[5];
            #pragma unroll
            for (int i=0;i<4;i++) a[i]=As[ty*4+i][kk];
            #pragma unroll
            for (int j=0;j<5;j++) bb[j]=Bs[kk][tx*5+j];
            #pragma unroll
            for (int i=0;i<4;i++)
                #pragma unroll
                for (int j=0;j<5;j++) acc[i][j]+=a[i]*bb[j];
        }
        __syncthreads();
    }
    #pragma unroll
    for (int i=0;i<4;i++){
        int r = rowblk + ty*4 + i;
        float rs = rowsum[r];
        #pragma unroll
        for (int j=0;j<5;j++){
            int col = tx*5 + j;
            if (col < 64) h1buf[(size_t)r*64 + col] = lrelu(rs*acc[i][j] + b1[col]);
            else          scbuf[(size_t)r*16 + (col-64)] = lrelu(acc[i][j] + scb[col-64]);
        }
    }
}

// ---------------- stage2: x2 = lrelu(h1@w2 + b2) + sc ; BN2 stats ----------------
__global__ __launch_bounds__(256)
void k_stage2(const float* __restrict__ h1buf, const float* __restrict__ scbuf,
              const float* __restrict__ w2, const float* __restrict__ b2,
              float* __restrict__ x2, float* __restrict__ colsum, float* __restrict__ colsq)
{
    __shared__ float Hs[64][65];
    __shared__ float Ws[64][17];
    __shared__ float red[16][16];
    int t = threadIdx.x;
    int rowblk = blockIdx.x * 64;
    #pragma unroll
    for (int l=0;l<4;l++){
        int idx = t + l*256;
        Ws[idx>>4][idx&15] = w2[idx];
    }
    #pragma unroll
    for (int l=0;l<16;l++){
        int idx = t + l*256;
        Hs[idx>>6][idx&63] = h1buf[(size_t)rowblk*64 + idx];
    }
    __syncthreads();
    int col = t & 15, rb = t >> 4;
    float ps=0.f, pq=0.f;
    #pragma unroll
    for (int gg=0; gg<4; gg++){
        int r = rb + gg*16;
        float s = b2[col];
        #pragma unroll
        for (int c=0;c<64;c++) s += Hs[r][c]*Ws[c][col];
        float v = lrelu(s) + scbuf[(size_t)(rowblk+r)*16 + col];
        x2[(size_t)(rowblk+r)*16 + col] = v;
        ps += v; pq += v*v;
    }
    red[rb][col] = ps; __syncthreads();
    if (t < 16){
        float s=0.f;
        for (int g=0; g<16; g++) s += red[g][t];
        atomicAdd(&colsum[t], s);
    }
    __syncthreads();
    red[rb][col] = pq; __syncthreads();
    if (t < 16){
        float s=0.f;
        for (int g=0; g<16; g++) s += red[g][t];
        atomicAdd(&colsq[t], s);
    }
}

// ---------------- attention: one block per (batch, head) ----------------
__global__ __launch_bounds__(256)
void k_attn(const float* __restrict__ x2, const float* __restrict__ s2, const float* __restrict__ h2,
            const float* __restrict__ cls,
            const float* __restrict__ wq, const float* __restrict__ bq,
            const float* __restrict__ wk, const float* __restrict__ bk,
            const float* __restrict__ wv, const float* __restrict__ bv,
            float* __restrict__ attn, float* __restrict__ obuf)
{
    int b = blockIdx.x >> 2;
    int h = blockIdx.x & 3;
    __shared__ float xin[NP1][16];
    __shared__ float qs[NP1][8];
    __shared__ float ks[NP1][8];
    __shared__ float vs[NP1][8];
    __shared__ float wqh[16][8], wkh[16][8], wvh[16][8];
    __shared__ float bqh[8], bkh[8], bvh[8];
    int t = threadIdx.x;
    if (t < 128){ int c = t>>3, d = t&7;
        wqh[c][d]=wq[c*32+h*8+d]; wkh[c][d]=wk[c*32+h*8+d]; wvh[c][d]=wv[c*32+h*8+d]; }
    if (t < 8){ bqh[t]=bq[h*8+t]; bkh[t]=bk[h*8+t]; bvh[t]=bv[h*8+t]; }
    for (int idx=t; idx < NP1*16; idx += 256){
        int r = idx>>4, c = idx&15;
        float v;
        if (r==0) v = cls[c];
        else v = x2[((size_t)b*NN + r-1)*16 + c]*s2[c] + h2[c];
        xin[r][c] = v;
    }
    __syncthreads();
    for (int idx=t; idx < NP1*8; idx += 256){
        int r = idx>>3, d = idx&7;
        float q=bqh[d], k=bkh[d], v=bvh[d];
        #pragma unroll
        for (int c=0;c<16;c++){
            float x = xin[r][c];
            q += x*wqh[c][d]; k += x*wkh[c][d]; v += x*wvh[c][d];
        }
        qs[r][d]=q; ks[r][d]=k; vs[r][d]=v;
    }
    __syncthreads();
    int wave = t >> 6, lane = t & 63;
    const float scale = 0.35355339059327373f;
    for (int qi = wave; qi < NP1; qi += 4){
        float qv[8];
        #pragma unroll
        for (int d=0;d<8;d++) qv[d]=qs[qi][d];
        float e[6];
        float mx = -1e30f;
        #pragma unroll
        for (int j=0;j<6;j++){
            int ki = lane + j*64;
            float s = -1e30f;
            if (ki < NP1){
                s = 0.f;
                #pragma unroll
                for (int d=0;d<8;d++) s += qv[d]*ks[ki][d];
                s *= scale;
            }
            e[j] = s;
            mx = fmaxf(mx, s);
        }
        #pragma unroll
        for (int off=32; off; off>>=1) mx = fmaxf(mx, __shfl_xor(mx, off));
        float sum = 0.f;
        #pragma unroll
        for (int j=0;j<6;j++){
            int ki = lane + j*64;
            float p = (ki < NP1) ? __expf(e[j]-mx) : 0.f;
            e[j] = p;
            sum += p;
        }
        #pragma unroll
        for (int off=32; off; off>>=1) sum += __shfl_xor(sum, off);
        float inv = 1.f / sum;
        size_t base = (((size_t)b*4 + h)*NP1 + qi)*NP1;
        float o[8] = {0,0,0,0,0,0,0,0};
        #pragma unroll
        for (int j=0;j<6;j++){
            int ki = lane + j*64;
            if (ki < NP1){
                float p = e[j]*inv;
                attn[base + ki] = p;
                #pragma unroll
                for (int d=0;d<8;d++) o[d] += e[j]*vs[ki][d];
            }
        }
        #pragma unroll
        for (int d=0;d<8;d++){
            #pragma unroll
            for (int off=32; off; off>>=1) o[d] += __shfl_xor(o[d], off);
        }
        if (lane == 0){
            #pragma unroll
            for (int d=0;d<8;d++)
                obuf[((size_t)b*NP1 + qi)*32 + h*8 + d] = o[d]*inv;
        }
    }
}

// ---------------- score (cls row) + sigmoid ----------------
__global__ void k_score(const float* __restrict__ attn, float* __restrict__ out_sig,
                        float* __restrict__ score_raw){
    int b = blockIdx.x;
    for (int j = threadIdx.x; j < NN; j += blockDim.x){
        float s = 0.f;
        #pragma unroll
        for (int h=0; h<4; h++)
            s += attn[(((size_t)b*4+h)*NP1)*NP1 + 1 + j];
        score_raw[b*NN + j] = s;
        out_sig[b*NN + j] = 1.f/(1.f + __expf(-s));
    }
}

// ---------------- top-k select + softmax pool + MLP head ----------------
__global__ __launch_bounds__(256)
void k_pool(const float* __restrict__ score_raw, const float* __restrict__ obuf,
            const float* __restrict__ wo, const float* __restrict__ bo,
            const float* __restrict__ f1w, const float* __restrict__ f1b,
            const float* __restrict__ f2w, const float* __restrict__ f2b,
            const float* __restrict__ f3w, const float* __restrict__ f3b,
            float* __restrict__ logits)
{
    int b = blockIdx.x;
    __shared__ float sc[NN];
    __shared__ float w[NN];
    __shared__ float red[256];
    __shared__ float pooled32[32];
    __shared__ float p16[16];
    __shared__ float h64[64];
    __shared__ float h32[32];
    int t = threadIdx.x;
    for (int i=t; i<NN; i+=256) sc[i] = score_raw[b*NN+i];
    __syncthreads();
    float mx = -1e30f;
    for (int i=t; i<NN; i+=256) mx = fmaxf(mx, sc[i]);
    red[t] = mx; __syncthreads();
    for (int s=128; s; s>>=1){ if (t<s) red[t]=fmaxf(red[t],red[t+s]); __syncthreads(); }
    mx = red[0];
    __syncthreads();
    float psum = 0.f;
    for (int i=t; i<NN; i+=256){
        float si = sc[i];
        int r = 0;
        for (int j=0;j<NN;j++){
            float sj = sc[j];
            r += (sj > si) || (sj == si && j < i);
        }
        float wi = (r < POOLL) ? __expf(si - mx) : 0.f;
        w[i] = wi;
        psum += wi;
    }
    red[t] = psum; __syncthreads();
    for (int s=128; s; s>>=1){ if (t<s) red[t]+=red[t+s]; __syncthreads(); }
    float inv = 1.f / red[0];
    __syncthreads();
    if (t < 32){
        float s = 0.f;
        for (int i=0;i<NN;i++) s += w[i] * obuf[((size_t)b*NP1 + 1 + i)*32 + t];
        pooled32[t] = s * inv;
    }
    __syncthreads();
    if (t < 16){
        float s = bo[t];
        for (int d=0;d<32;d++) s += pooled32[d]*wo[d*16+t];
        p16[t] = s;
    }
    __syncthreads();
    if (t < 64){
        float s = f1b[t];
        for (int c=0;c<16;c++) s += p16[c]*f1w[c*64+t];
        h64[t] = lrelu(s);
    }
    __syncthreads();
    if (t < 32){
        float s = f2b[t];
        for (int c=0;c<64;c++) s += h64[c]*f2w[c*32+t];
        h32[t] = lrelu(s);
    }
    __syncthreads();
    if (t < 2){
        float s = f3b[t];
        for (int c=0;c<32;c++) s += h32[c]*f3w[c*2+t];
        logits[b*2+t] = s;
    }
}

extern "C" void kernel_launch(void* const* d_in, const int* in_sizes, int n_in,
                              void* d_out, int out_size, void* d_ws, size_t ws_size,
                              hipStream_t stream)
{
    const float* m    = (const float*)d_in[0];
    const float* nf   = (const float*)d_in[1];
    const float* cls  = (const float*)d_in[2];
    const float* g0w  = (const float*)d_in[3];
    const float* g0b  = (const float*)d_in[4];
    const float* g1w  = (const float*)d_in[5];
    const float* g1b  = (const float*)d_in[6];
    const float* g2w1 = (const float*)d_in[7];
    const float* g2b1 = (const float*)d_in[8];
    const float* g2w2 = (const float*)d_in[9];
    const float* g2b2 = (const float*)d_in[10];
    const float* scw  = (const float*)d_in[11];
    const float* scb  = (const float*)d_in[12];
    const float* bn0g = (const float*)d_in[13];
    const float* bn0b = (const float*)d_in[14];
    const float* bn1g = (const float*)d_in[15];
    const float* bn1b = (const float*)d_in[16];
    const float* bn2g = (const float*)d_in[17];
    const float* bn2b = (const float*)d_in[18];
    const float* wq = (const float*)d_in[19];
    const float* bq = (const float*)d_in[20];
    const float* wk = (const float*)d_in[21];
    const float* bk = (const float*)d_in[22];
    const float* wv = (const float*)d_in[23];
    const float* bv = (const float*)d_in[24];
    const float* wo = (const float*)d_in[25];
    const float* bo = (const float*)d_in[26];
    const float* f1w = (const float*)d_in[27];
    const float* f1b = (const float*)d_in[28];
    const float* f2w = (const float*)d_in[29];
    const float* f2b = (const float*)d_in[30];
    const float* f3w = (const float*)d_in[31];
    const float* f3b = (const float*)d_in[32];

    float* out_logits = (float*)d_out;
    float* out_sig = out_logits + 512;
    float* attn = out_sig + (size_t)BZ*NN;

    // large scratch lives inside the attn output region (dead before attn write)
    float* y0    = attn;
    float* y1    = attn + (size_t)MROWS*NN;
    float* h1buf = attn + (size_t)2*MROWS*NN;
    float* scbuf = h1buf + (size_t)MROWS*64;

    float* ws = (float*)d_ws;
    float* rowsum = ws;                ws += MROWS;
    float* stats  = ws;                ws += 1472;
    float* cs0 = stats, *cq0 = stats+360, *cs1 = stats+720, *cq1 = stats+1080,
         * cs2 = stats+1440, *cq2 = stats+1456;
    float* s0 = ws;  ws += 360;
    float* h0 = ws;  ws += 360;
    float* s1 = ws;  ws += 360;
    float* hh1 = ws; ws += 360;
    float* s2 = ws;  ws += 16;
    float* h2 = ws;  ws += 16;
    float* x2 = ws;       ws += (size_t)MROWS*16;
    float* obuf = ws;     ws += (size_t)BZ*NP1*32;
    float* score_raw = ws; ws += (size_t)BZ*NN;

    k_zero<<<6, 256, 0, stream>>>(stats, 1472);
    k_rowsum<<<MROWS/4, 256, 0, stream>>>(m, rowsum);
    dim3 g1(720, 6);
    k_gemm_big<false,false><<<g1, 256, 0, stream>>>(nf, g0w, g0b, rowsum, s0, h0, y0, cs0, cq0);
    k_bnfin<<<1, 384, 0, stream>>>(cs0, cq0, bn0g, bn0b, 360, s0, h0);
    k_gemm_big<true,true><<<g1, 256, 0, stream>>>(y0, g1w, g1b, rowsum, s0, h0, y1, cs1, cq1);
    k_bnfin<<<1, 384, 0, stream>>>(cs1, cq1, bn1g, bn1b, 360, s1, hh1);
    k_gemm2<<<1440, 256, 0, stream>>>(y1, g2w1, scw, g2b1, scb, rowsum, s1, hh1, h1buf, scbuf);
    k_stage2<<<1440, 256, 0, stream>>>(h1buf, scbuf, g2w2, g2b2, x2, cs2, cq2);
    k_bnfin<<<1, 64, 0, stream>>>(cs2, cq2, bn2g, bn2b, 16, s2, h2);
    k_attn<<<BZ*4, 256, 0, stream>>>(x2, s2, h2, cls, wq, bq, wk, bk, wv, bv, attn, obuf);
    k_score<<<BZ, 256, 0, stream>>>(attn, out_sig, score_raw);
    k_pool<<<BZ, 256, 0, stream>>>(score_raw, obuf, wo, bo, f1w, f1b, f2w, f2b, f3w, f3b, out_logits);
}

// Round 3
// 989.078 us; speedup vs baseline: 2.7423x; 2.7423x over previous
//
#include <hip/hip_runtime.h>
#include <math.h>

#define BZ 256
#define NN 360
#define NP1 361
#define MROWS (BZ*NN)   // 92160
#define POOLL 252
#define KP 384          // padded K (12 tiles of 32)

typedef __attribute__((ext_vector_type(8))) short bf16x8;
typedef __attribute__((ext_vector_type(4))) float f32x4;

__device__ __forceinline__ float lrelu(float x){ return x > 0.f ? x : 0.2f*x; }

__device__ __forceinline__ ushort f2bf(float f){
    union { float f; uint u; } v; v.f = f;
    uint u = v.u + 0x7FFFu + ((v.u >> 16) & 1u);
    return (ushort)(u >> 16);
}
__device__ __forceinline__ float bf2f(ushort h){
    union { uint u; float f; } v; v.u = ((uint)h) << 16;
    return v.f;
}
__device__ __forceinline__ void split2(float v, ushort& hi, ushort& lo){
    hi = f2bf(v);
    lo = f2bf(v - bf2f(hi));
}

// ---------------- zero small stats area ----------------
__global__ void k_zero(float* p, int n){
    int i = blockIdx.x*blockDim.x + threadIdx.x;
    if (i < n) p[i] = 0.f;
}

// ---------------- rowsum: one wave per row ----------------
__global__ __launch_bounds__(256)
void k_rowsum(const float* __restrict__ m, float* __restrict__ rowsum){
    int wid = (blockIdx.x*blockDim.x + threadIdx.x) >> 6;
    int lane = threadIdx.x & 63;
    if (wid >= MROWS) return;
    const float* p = m + (size_t)wid*NN;
    float s = 0.f;
    for (int j = lane; j < NN; j += 64) s += p[j];
    #pragma unroll
    for (int off = 32; off; off >>= 1) s += __shfl_down(s, off);
    if (lane == 0) rowsum[wid] = s;
}

// ---------------- weight prep: Wt hi/lo [j][k] = split(s[k]*W[k][j]), c[j] = sum_k h[k]*W[k][j] ----------------
__global__ __launch_bounds__(384)
void k_prepw(const float* __restrict__ W, int ncols, int joff,
             const float* __restrict__ s, const float* __restrict__ h,
             ushort* __restrict__ Wth, ushort* __restrict__ Wtl, float* __restrict__ cvec)
{
    int j = blockIdx.x;
    int k = threadIdx.x;      // 0..383
    __shared__ float red[6];
    float wv = 0.f, hv = 0.f, sv = 1.f;
    if (k < NN && j < ncols){
        wv = W[(size_t)k*ncols + j];
        if (s) sv = s[k];
        if (h) hv = h[k];
    }
    ushort hi, lo; split2(wv * sv, hi, lo);
    Wth[(size_t)(joff + j)*KP + k] = hi;
    Wtl[(size_t)(joff + j)*KP + k] = lo;
    float v = hv * wv;
    #pragma unroll
    for (int off = 32; off; off >>= 1) v += __shfl_down(v, off);
    int lane = k & 63, wid = k >> 6;
    if (lane == 0) red[wid] = v;
    __syncthreads();
    if (k == 0) cvec[joff + j] = red[0]+red[1]+red[2]+red[3]+red[4]+red[5];
}

// ---------------- big MFMA GEMM, split-bf16 (3-term) ----------------
// Y = lrelu(rs[i]*((A@Wt^T)[i][j] + c[j]) + bias[j]) (+ s[j]*A[i][j]+h[j] resid)
// out: bf16 hi/lo pair (KP stride), + col stats (on exact fp32 v)
template<bool AF32, bool RESID>
__global__ __launch_bounds__(256)
void k_gemm_mfma(const void* __restrict__ Avh, const ushort* __restrict__ Avl,
                 const ushort* __restrict__ Wth, const ushort* __restrict__ Wtl,
                 const float* __restrict__ cvec, const float* __restrict__ bias,
                 const float* __restrict__ rowsum,
                 const float* __restrict__ bns, const float* __restrict__ bnh,
                 ushort* __restrict__ Yhi, ushort* __restrict__ Ylo,
                 float* __restrict__ colsum, float* __restrict__ colsq)
{
    __shared__ ushort Ah[128][40];   // rows padded to 80B -> conflict-free b128
    __shared__ ushort Al[128][40];
    __shared__ ushort Bh[64][40];
    __shared__ ushort Bl[64][40];
    int t = threadIdx.x;
    int w = t >> 6, lane = t & 63;
    int l15 = lane & 15, g = lane >> 4;
    int rowblk = blockIdx.x * 128;
    int colblk = blockIdx.y * 64;

    f32x4 acc[2][4];
    #pragma unroll
    for (int i=0;i<2;i++)
        #pragma unroll
        for (int j=0;j<4;j++)
            #pragma unroll
            for (int e=0;e<4;e++) acc[i][j][e] = 0.f;

    int sr = t >> 1;            // A-stage row 0..127
    int sk = (t & 1) * 16;      // A-stage k offset 0/16
    int bc = t >> 2;            // B-stage col 0..63
    int bk = (t & 3) * 8;       // B-stage k offset

    for (int kt = 0; kt < 12; ++kt){
        int k0 = kt * 32;
        if (AF32){
            const float* A = (const float*)Avh;
            uint ph[8], pl[8];
            #pragma unroll
            for (int c=0;c<4;c++){
                int k = k0 + sk + c*4;
                float4 f = make_float4(0.f,0.f,0.f,0.f);
                if (k < NN) f = *(const float4*)&A[(size_t)(rowblk+sr)*NN + k];
                ushort hx,lx,hy,ly,hz,lz,hw,lw;
                split2(f.x,hx,lx); split2(f.y,hy,ly); split2(f.z,hz,lz); split2(f.w,hw,lw);
                ph[c*2]   = (uint)hx | ((uint)hy<<16);
                ph[c*2+1] = (uint)hz | ((uint)hw<<16);
                pl[c*2]   = (uint)lx | ((uint)ly<<16);
                pl[c*2+1] = (uint)lz | ((uint)lw<<16);
            }
            ((uint4*)&Ah[sr][sk])[0]   = make_uint4(ph[0],ph[1],ph[2],ph[3]);
            ((uint4*)&Ah[sr][sk+8])[0] = make_uint4(ph[4],ph[5],ph[6],ph[7]);
            ((uint4*)&Al[sr][sk])[0]   = make_uint4(pl[0],pl[1],pl[2],pl[3]);
            ((uint4*)&Al[sr][sk+8])[0] = make_uint4(pl[4],pl[5],pl[6],pl[7]);
        } else {
            const ushort* AH = (const ushort*)Avh;
            const size_t base = (size_t)(rowblk+sr)*KP + k0 + sk;
            ((int4*)&Ah[sr][sk])[0]   = *(const int4*)&AH[base];
            ((int4*)&Ah[sr][sk+8])[0] = *(const int4*)&AH[base + 8];
            ((int4*)&Al[sr][sk])[0]   = *(const int4*)&Avl[base];
            ((int4*)&Al[sr][sk+8])[0] = *(const int4*)&Avl[base + 8];
        }
        ((int4*)&Bh[bc][bk])[0] = *(const int4*)&Wth[(size_t)(colblk+bc)*KP + k0 + bk];
        ((int4*)&Bl[bc][bk])[0] = *(const int4*)&Wtl[(size_t)(colblk+bc)*KP + k0 + bk];
        __syncthreads();

        bf16x8 ah0 = *(const bf16x8*)&Ah[32*w + l15][8*g];
        bf16x8 ah1 = *(const bf16x8*)&Ah[32*w + 16 + l15][8*g];
        bf16x8 al0 = *(const bf16x8*)&Al[32*w + l15][8*g];
        bf16x8 al1 = *(const bf16x8*)&Al[32*w + 16 + l15][8*g];
        #pragma unroll
        for (int nj=0;nj<4;nj++){
            bf16x8 bh = *(const bf16x8*)&Bh[16*nj + l15][8*g];
            bf16x8 bl = *(const bf16x8*)&Bl[16*nj + l15][8*g];
            acc[0][nj] = __builtin_amdgcn_mfma_f32_16x16x32_bf16(ah0, bh, acc[0][nj], 0, 0, 0);
            acc[0][nj] = __builtin_amdgcn_mfma_f32_16x16x32_bf16(al0, bh, acc[0][nj], 0, 0, 0);
            acc[0][nj] = __builtin_amdgcn_mfma_f32_16x16x32_bf16(ah0, bl, acc[0][nj], 0, 0, 0);
            acc[1][nj] = __builtin_amdgcn_mfma_f32_16x16x32_bf16(ah1, bh, acc[1][nj], 0, 0, 0);
            acc[1][nj] = __builtin_amdgcn_mfma_f32_16x16x32_bf16(al1, bh, acc[1][nj], 0, 0, 0);
            acc[1][nj] = __builtin_amdgcn_mfma_f32_16x16x32_bf16(ah1, bl, acc[1][nj], 0, 0, 0);
        }
        __syncthreads();
    }

    // epilogue
    const ushort* AHg = (const ushort*)Avh;
    float cs_part[4] = {0,0,0,0}, cq_part[4] = {0,0,0,0};
    #pragma unroll
    for (int mi=0;mi<2;mi++){
        #pragma unroll
        for (int nj=0;nj<4;nj++){
            f32x4 d = acc[mi][nj];
            #pragma unroll
            for (int r=0;r<4;r++){
                int row = rowblk + 32*w + 16*mi + 4*g + r;
                int col = colblk + 16*nj + l15;
                float v = 0.f;
                if (col < NN){
                    float pre = rowsum[row] * (d[r] + cvec[col]) + bias[col];
                    v = lrelu(pre);
                    if (RESID){
                        size_t ai = (size_t)row*KP + col;
                        float ar = bf2f(AHg[ai]) + bf2f(Avl[ai]);
                        v += ar * bns[col] + bnh[col];
                    }
                }
                ushort hi, lo; split2(v, hi, lo);
                Yhi[(size_t)row*KP + col] = hi;
                Ylo[(size_t)row*KP + col] = lo;
                cs_part[nj] += v;
                cq_part[nj] += v*v;
            }
        }
    }
    // reduce stats: over g (xor 16,32), then across waves via LDS
    #pragma unroll
    for (int nj=0;nj<4;nj++){
        cs_part[nj] += __shfl_xor(cs_part[nj], 16); cs_part[nj] += __shfl_xor(cs_part[nj], 32);
        cq_part[nj] += __shfl_xor(cq_part[nj], 16); cq_part[nj] += __shfl_xor(cq_part[nj], 32);
    }
    float* red = (float*)&Ah[0][0];
    if (lane < 16){
        #pragma unroll
        for (int nj=0;nj<4;nj++) red[w*64 + nj*16 + l15] = cs_part[nj];
    }
    __syncthreads();
    if (t < 64 && colblk + t < NN)
        atomicAdd(&colsum[colblk + t], red[t] + red[64+t] + red[128+t] + red[192+t]);
    __syncthreads();
    if (lane < 16){
        #pragma unroll
        for (int nj=0;nj<4;nj++) red[w*64 + nj*16 + l15] = cq_part[nj];
    }
    __syncthreads();
    if (t < 64 && colblk + t < NN)
        atomicAdd(&colsq[colblk + t], red[t] + red[64+t] + red[128+t] + red[192+t]);
}

// ---------------- BN finalize ----------------
__global__ void k_bnfin(const float* __restrict__ colsum, const float* __restrict__ colsq,
                        const float* __restrict__ g, const float* __restrict__ b, int ncols,
                        float* __restrict__ scale, float* __restrict__ shift){
    int j = blockIdx.x*blockDim.x + threadIdx.x;
    if (j >= ncols) return;
    float mu = colsum[j] / (float)MROWS;
    float var = colsq[j] / (float)MROWS - mu*mu;
    float sc = g[j] * rsqrtf(var + 1e-5f);
    scale[j] = sc;
    shift[j] = b[j] - mu*sc;
}

// ---------------- gemm2: y1(hi/lo) @ Wt2^T(80x384 hi/lo) -> h1 (cols 0-63, f32) + sc (cols 64-79, f32) ----------------
__global__ __launch_bounds__(256)
void k_gemm2_mfma(const ushort* __restrict__ AH, const ushort* __restrict__ AL,
                  const ushort* __restrict__ Wth, const ushort* __restrict__ Wtl,
                  const float* __restrict__ cvec, const float* __restrict__ b1,
                  const float* __restrict__ scb, const float* __restrict__ rowsum,
                  float* __restrict__ h1buf, float* __restrict__ scbuf)
{
    __shared__ ushort Ah[128][40];
    __shared__ ushort Al[128][40];
    __shared__ ushort Bh[80][40];
    __shared__ ushort Bl[80][40];
    int t = threadIdx.x;
    int w = t >> 6, lane = t & 63;
    int l15 = lane & 15, g = lane >> 4;
    int rowblk = blockIdx.x * 128;

    f32x4 acc[2][5];
    #pragma unroll
    for (int i=0;i<2;i++)
        #pragma unroll
        for (int j=0;j<5;j++)
            #pragma unroll
            for (int e=0;e<4;e++) acc[i][j][e] = 0.f;

    int sr = t >> 1, sk = (t & 1) * 16;

    for (int kt = 0; kt < 12; ++kt){
        int k0 = kt * 32;
        {
            const size_t base = (size_t)(rowblk+sr)*KP + k0 + sk;
            ((int4*)&Ah[sr][sk])[0]   = *(const int4*)&AH[base];
            ((int4*)&Ah[sr][sk+8])[0] = *(const int4*)&AH[base + 8];
            ((int4*)&Al[sr][sk])[0]   = *(const int4*)&AL[base];
            ((int4*)&Al[sr][sk+8])[0] = *(const int4*)&AL[base + 8];
        }
        #pragma unroll
        for (int l=0;l<2;l++){
            int c = t + l*256;
            if (c < 320){
                int col = c >> 2, kk = (c & 3)*8;
                ((int4*)&Bh[col][kk])[0] = *(const int4*)&Wth[(size_t)col*KP + k0 + kk];
                ((int4*)&Bl[col][kk])[0] = *(const int4*)&Wtl[(size_t)col*KP + k0 + kk];
            }
        }
        __syncthreads();
        bf16x8 ah0 = *(const bf16x8*)&Ah[32*w + l15][8*g];
        bf16x8 ah1 = *(const bf16x8*)&Ah[32*w + 16 + l15][8*g];
        bf16x8 al0 = *(const bf16x8*)&Al[32*w + l15][8*g];
        bf16x8 al1 = *(const bf16x8*)&Al[32*w + 16 + l15][8*g];
        #pragma unroll
        for (int nj=0;nj<5;nj++){
            bf16x8 bh = *(const bf16x8*)&Bh[16*nj + l15][8*g];
            bf16x8 bl = *(const bf16x8*)&Bl[16*nj + l15][8*g];
            acc[0][nj] = __builtin_amdgcn_mfma_f32_16x16x32_bf16(ah0, bh, acc[0][nj], 0, 0, 0);
            acc[0][nj] = __builtin_amdgcn_mfma_f32_16x16x32_bf16(al0, bh, acc[0][nj], 0, 0, 0);
            acc[0][nj] = __builtin_amdgcn_mfma_f32_16x16x32_bf16(ah0, bl, acc[0][nj], 0, 0, 0);
            acc[1][nj] = __builtin_amdgcn_mfma_f32_16x16x32_bf16(ah1, bh, acc[1][nj], 0, 0, 0);
            acc[1][nj] = __builtin_amdgcn_mfma_f32_16x16x32_bf16(al1, bh, acc[1][nj], 0, 0, 0);
            acc[1][nj] = __builtin_amdgcn_mfma_f32_16x16x32_bf16(ah1, bl, acc[1][nj], 0, 0, 0);
        }
        __syncthreads();
    }

    #pragma unroll
    for (int mi=0;mi<2;mi++){
        #pragma unroll
        for (int nj=0;nj<5;nj++){
            f32x4 d = acc[mi][nj];
            #pragma unroll
            for (int r=0;r<4;r++){
                int row = rowblk + 32*w + 16*mi + 4*g + r;
                int col = 16*nj + l15;
                if (nj < 4){
                    float pre = rowsum[row] * (d[r] + cvec[col]) + b1[col];
                    h1buf[(size_t)row*64 + col] = lrelu(pre);
                } else {
                    int cc = col - 64;
                    float pre = d[r] + cvec[col] + scb[cc];
                    scbuf[(size_t)row*16 + cc] = lrelu(pre);
                }
            }
        }
    }
}

// ---------------- stage2: x2 = lrelu(h1@w2 + b2) + sc ; BN2 stats ----------------
__global__ __launch_bounds__(256)
void k_stage2(const float* __restrict__ h1buf, const float* __restrict__ scbuf,
              const float* __restrict__ w2, const float* __restrict__ b2,
              float* __restrict__ x2, float* __restrict__ colsum, float* __restrict__ colsq)
{
    __shared__ float Hs[64][65];
    __shared__ float Ws[64][17];
    __shared__ float red[16][16];
    int t = threadIdx.x;
    int rowblk = blockIdx.x * 64;
    #pragma unroll
    for (int l=0;l<4;l++){
        int idx = t + l*256;
        Ws[idx>>4][idx&15] = w2[idx];
    }
    #pragma unroll
    for (int l=0;l<16;l++){
        int idx = t + l*256;
        Hs[idx>>6][idx&63] = h1buf[(size_t)rowblk*64 + idx];
    }
    __syncthreads();
    int col = t & 15, rb = t >> 4;
    float ps=0.f, pq=0.f;
    #pragma unroll
    for (int gg=0; gg<4; gg++){
        int r = rb + gg*16;
        float s = b2[col];
        #pragma unroll
        for (int c=0;c<64;c++) s += Hs[r][c]*Ws[c][col];
        float v = lrelu(s) + scbuf[(size_t)(rowblk+r)*16 + col];
        x2[(size_t)(rowblk+r)*16 + col] = v;
        ps += v; pq += v*v;
    }
    red[rb][col] = ps; __syncthreads();
    if (t < 16){
        float s=0.f;
        for (int g=0; g<16; g++) s += red[g][t];
        atomicAdd(&colsum[t], s);
    }
    __syncthreads();
    red[rb][col] = pq; __syncthreads();
    if (t < 16){
        float s=0.f;
        for (int g=0; g<16; g++) s += red[g][t];
        atomicAdd(&colsq[t], s);
    }
}

// ---------------- attention: one block per (batch, head) ----------------
__global__ __launch_bounds__(256)
void k_attn(const float* __restrict__ x2, const float* __restrict__ s2, const float* __restrict__ h2,
            const float* __restrict__ cls,
            const float* __restrict__ wq, const float* __restrict__ bq,
            const float* __restrict__ wk, const float* __restrict__ bk,
            const float* __restrict__ wv, const float* __restrict__ bv,
            float* __restrict__ attn, float* __restrict__ obuf)
{
    int b = blockIdx.x >> 2;
    int h = blockIdx.x & 3;
    __shared__ float xin[NP1][16];
    __shared__ float qs[NP1][8];
    __shared__ float ks[NP1][8];
    __shared__ float vs[NP1][8];
    __shared__ float wqh[16][8], wkh[16][8], wvh[16][8];
    __shared__ float bqh[8], bkh[8], bvh[8];
    int t = threadIdx.x;
    if (t < 128){ int c = t>>3, d = t&7;
        wqh[c][d]=wq[c*32+h*8+d]; wkh[c][d]=wk[c*32+h*8+d]; wvh[c][d]=wv[c*32+h*8+d]; }
    if (t < 8){ bqh[t]=bq[h*8+t]; bkh[t]=bk[h*8+t]; bvh[t]=bv[h*8+t]; }
    for (int idx=t; idx < NP1*16; idx += 256){
        int r = idx>>4, c = idx&15;
        float v;
        if (r==0) v = cls[c];
        else v = x2[((size_t)b*NN + r-1)*16 + c]*s2[c] + h2[c];
        xin[r][c] = v;
    }
    __syncthreads();
    for (int idx=t; idx < NP1*8; idx += 256){
        int r = idx>>3, d = idx&7;
        float q=bqh[d], k=bkh[d], v=bvh[d];
        #pragma unroll
        for (int c=0;c<16;c++){
            float x = xin[r][c];
            q += x*wqh[c][d]; k += x*wkh[c][d]; v += x*wvh[c][d];
        }
        qs[r][d]=q; ks[r][d]=k; vs[r][d]=v;
    }
    __syncthreads();
    int wave = t >> 6, lane = t & 63;
    const float scale = 0.35355339059327373f;
    for (int qi = wave; qi < NP1; qi += 4){
        float qv[8];
        #pragma unroll
        for (int d=0;d<8;d++) qv[d]=qs[qi][d];
        float e[6];
        float mx = -1e30f;
        #pragma unroll
        for (int j=0;j<6;j++){
            int ki = lane + j*64;
            float s = -1e30f;
            if (ki < NP1){
                s = 0.f;
                #pragma unroll
                for (int d=0;d<8;d++) s += qv[d]*ks[ki][d];
                s *= scale;
            }
            e[j] = s;
            mx = fmaxf(mx, s);
        }
        #pragma unroll
        for (int off=32; off; off>>=1) mx = fmaxf(mx, __shfl_xor(mx, off));
        float sum = 0.f;
        #pragma unroll
        for (int j=0;j<6;j++){
            int ki = lane + j*64;
            float p = (ki < NP1) ? __expf(e[j]-mx) : 0.f;
            e[j] = p;
            sum += p;
        }
        #pragma unroll
        for (int off=32; off; off>>=1) sum += __shfl_xor(sum, off);
        float inv = 1.f / sum;
        size_t base = (((size_t)b*4 + h)*NP1 + qi)*NP1;
        float o[8] = {0,0,0,0,0,0,0,0};
        #pragma unroll
        for (int j=0;j<6;j++){
            int ki = lane + j*64;
            if (ki < NP1){
                float p = e[j]*inv;
                attn[base + ki] = p;
                #pragma unroll
                for (int d=0;d<8;d++) o[d] += e[j]*vs[ki][d];
            }
        }
        #pragma unroll
        for (int d=0;d<8;d++){
            #pragma unroll
            for (int off=32; off; off>>=1) o[d] += __shfl_xor(o[d], off);
        }
        if (lane == 0){
            #pragma unroll
            for (int d=0;d<8;d++)
                obuf[((size_t)b*NP1 + qi)*32 + h*8 + d] = o[d]*inv;
        }
    }
}

// ---------------- score (cls row) + sigmoid ----------------
__global__ void k_score(const float* __restrict__ attn, float* __restrict__ out_sig,
                        float* __restrict__ score_raw){
    int b = blockIdx.x;
    for (int j = threadIdx.x; j < NN; j += blockDim.x){
        float s = 0.f;
        #pragma unroll
        for (int h=0; h<4; h++)
            s += attn[(((size_t)b*4+h)*NP1)*NP1 + 1 + j];
        score_raw[b*NN + j] = s;
        out_sig[b*NN + j] = 1.f/(1.f + __expf(-s));
    }
}

// ---------------- top-k select + softmax pool + MLP head ----------------
__global__ __launch_bounds__(256)
void k_pool(const float* __restrict__ score_raw, const float* __restrict__ obuf,
            const float* __restrict__ wo, const float* __restrict__ bo,
            const float* __restrict__ f1w, const float* __restrict__ f1b,
            const float* __restrict__ f2w, const float* __restrict__ f2b,
            const float* __restrict__ f3w, const float* __restrict__ f3b,
            float* __restrict__ logits)
{
    int b = blockIdx.x;
    __shared__ float sc[NN];
    __shared__ float w[NN];
    __shared__ float red[256];
    __shared__ float pooled32[32];
    __shared__ float p16[16];
    __shared__ float h64[64];
    __shared__ float h32[32];
    int t = threadIdx.x;
    for (int i=t; i<NN; i+=256) sc[i] = score_raw[b*NN+i];
    __syncthreads();
    float mx = -1e30f;
    for (int i=t; i<NN; i+=256) mx = fmaxf(mx, sc[i]);
    red[t] = mx; __syncthreads();
    for (int s=128; s; s>>=1){ if (t<s) red[t]=fmaxf(red[t],red[t+s]); __syncthreads(); }
    mx = red[0];
    __syncthreads();
    float psum = 0.f;
    for (int i=t; i<NN; i+=256){
        float si = sc[i];
        int r = 0;
        for (int j=0;j<NN;j++){
            float sj = sc[j];
            r += (sj > si) || (sj == si && j < i);
        }
        float wi = (r < POOLL) ? __expf(si - mx) : 0.f;
        w[i] = wi;
        psum += wi;
    }
    red[t] = psum; __syncthreads();
    for (int s=128; s; s>>=1){ if (t<s) red[t]+=red[t+s]; __syncthreads(); }
    float inv = 1.f / red[0];
    __syncthreads();
    if (t < 32){
        float s = 0.f;
        for (int i=0;i<NN;i++) s += w[i] * obuf[((size_t)b*NP1 + 1 + i)*32 + t];
        pooled32[t] = s * inv;
    }
    __syncthreads();
    if (t < 16){
        float s = bo[t];
        for (int d=0;d<32;d++) s += pooled32[d]*wo[d*16+t];
        p16[t] = s;
    }
    __syncthreads();
    if (t < 64){
        float s = f1b[t];
        for (int c=0;c<16;c++) s += p16[c]*f1w[c*64+t];
        h64[t] = lrelu(s);
    }
    __syncthreads();
    if (t < 32){
        float s = f2b[t];
        for (int c=0;c<64;c++) s += h64[c]*f2w[c*32+t];
        h32[t] = lrelu(s);
    }
    __syncthreads();
    if (t < 2){
        float s = f3b[t];
        for (int c=0;c<32;c++) s += h32[c]*f3w[c*2+t];
        logits[b*2+t] = s;
    }
}

extern "C" void kernel_launch(void* const* d_in, const int* in_sizes, int n_in,
                              void* d_out, int out_size, void* d_ws, size_t ws_size,
                              hipStream_t stream)
{
    const float* m    = (const float*)d_in[0];
    const float* nf   = (const float*)d_in[1];
    const float* cls  = (const float*)d_in[2];
    const float* g0w  = (const float*)d_in[3];
    const float* g0b  = (const float*)d_in[4];
    const float* g1w  = (const float*)d_in[5];
    const float* g1b  = (const float*)d_in[6];
    const float* g2w1 = (const float*)d_in[7];
    const float* g2b1 = (const float*)d_in[8];
    const float* g2w2 = (const float*)d_in[9];
    const float* g2b2 = (const float*)d_in[10];
    const float* scw  = (const float*)d_in[11];
    const float* scb  = (const float*)d_in[12];
    const float* bn0g = (const float*)d_in[13];
    const float* bn0b = (const float*)d_in[14];
    const float* bn1g = (const float*)d_in[15];
    const float* bn1b = (const float*)d_in[16];
    const float* bn2g = (const float*)d_in[17];
    const float* bn2b = (const float*)d_in[18];
    const float* wq = (const float*)d_in[19];
    const float* bq = (const float*)d_in[20];
    const float* wk = (const float*)d_in[21];
    const float* bk = (const float*)d_in[22];
    const float* wv = (const float*)d_in[23];
    const float* bv = (const float*)d_in[24];
    const float* wo = (const float*)d_in[25];
    const float* bo = (const float*)d_in[26];
    const float* f1w = (const float*)d_in[27];
    const float* f1b = (const float*)d_in[28];
    const float* f2w = (const float*)d_in[29];
    const float* f2b = (const float*)d_in[30];
    const float* f3w = (const float*)d_in[31];
    const float* f3b = (const float*)d_in[32];

    float* out_logits = (float*)d_out;
    float* out_sig = out_logits + 512;
    float* attn = out_sig + (size_t)BZ*NN;

    // big scratch inside the attn output region (dead until k_attn writes it)
    char* base = (char*)attn;
    const size_t szy = (size_t)MROWS * KP * 2;            // 70.8 MB per bf16 plane
    ushort* y0h = (ushort*)base;
    ushort* y0l = (ushort*)(base + szy);
    ushort* y1h = (ushort*)(base + 2*szy);
    ushort* y1l = (ushort*)(base + 3*szy);
    float*  h1buf = (float*)(base + 4*szy);               // 23.6 MB
    const size_t szh = (size_t)MROWS * 64 * 4;
    float*  scbuf = (float*)(base + 4*szy + szh);         // 5.9 MB
    const size_t szsc = (size_t)MROWS * 16 * 4;
    ushort* Wt0h = (ushort*)(base + 4*szy + szh + szsc);
    ushort* Wt0l = Wt0h + (size_t)KP*KP;
    ushort* Wt1h = Wt0l + (size_t)KP*KP;
    ushort* Wt1l = Wt1h + (size_t)KP*KP;
    ushort* Wt2h = Wt1l + (size_t)KP*KP;
    ushort* Wt2l = Wt2h + (size_t)KP*KP;
    float*  c0  = (float*)(Wt2l + (size_t)KP*KP);
    float*  c1  = c0 + KP;
    float*  c2  = c1 + KP;

    float* ws = (float*)d_ws;
    float* rowsum = ws;                ws += MROWS;
    float* stats  = ws;                ws += 1472;
    float* cs0 = stats, *cq0 = stats+360, *cs1 = stats+720, *cq1 = stats+1080,
         * cs2 = stats+1440, *cq2 = stats+1456;
    float* s0 = ws;  ws += 360;
    float* h0 = ws;  ws += 360;
    float* s1 = ws;  ws += 360;
    float* hh1 = ws; ws += 360;
    float* s2 = ws;  ws += 16;
    float* h2 = ws;  ws += 16;
    float* x2 = ws;       ws += (size_t)MROWS*16;
    float* obuf = ws;     ws += (size_t)BZ*NP1*32;
    float* score_raw = ws; ws += (size_t)BZ*NN;

    k_zero<<<6, 256, 0, stream>>>(stats, 1472);
    k_rowsum<<<MROWS/4, 256, 0, stream>>>(m, rowsum);
    k_prepw<<<KP, KP, 0, stream>>>(g0w, 360, 0, nullptr, nullptr, Wt0h, Wt0l, c0);

    dim3 g1(720, 6);
    k_gemm_mfma<true,false><<<g1, 256, 0, stream>>>(nf, nullptr, Wt0h, Wt0l, c0, g0b, rowsum, nullptr, nullptr, y0h, y0l, cs0, cq0);
    k_bnfin<<<1, 384, 0, stream>>>(cs0, cq0, bn0g, bn0b, 360, s0, h0);
    k_prepw<<<KP, KP, 0, stream>>>(g1w, 360, 0, s0, h0, Wt1h, Wt1l, c1);
    k_gemm_mfma<false,true><<<g1, 256, 0, stream>>>(y0h, y0l, Wt1h, Wt1l, c1, g1b, rowsum, s0, h0, y1h, y1l, cs1, cq1);
    k_bnfin<<<1, 384, 0, stream>>>(cs1, cq1, bn1g, bn1b, 360, s1, hh1);
    k_prepw<<<64, KP, 0, stream>>>(g2w1, 64, 0, s1, hh1, Wt2h, Wt2l, c2);
    k_prepw<<<16, KP, 0, stream>>>(scw, 16, 64, s1, hh1, Wt2h, Wt2l, c2);
    k_gemm2_mfma<<<720, 256, 0, stream>>>(y1h, y1l, Wt2h, Wt2l, c2, g2b1, scb, rowsum, h1buf, scbuf);
    k_stage2<<<1440, 256, 0, stream>>>(h1buf, scbuf, g2w2, g2b2, x2, cs2, cq2);
    k_bnfin<<<1, 64, 0, stream>>>(cs2, cq2, bn2g, bn2b, 16, s2, h2);
    k_attn<<<BZ*4, 256, 0, stream>>>(x2, s2, h2, cls, wq, bq, wk, bk, wv, bv, attn, obuf);
    k_score<<<BZ, 256, 0, stream>>>(attn, out_sig, score_raw);
    k_pool<<<BZ, 256, 0, stream>>>(score_raw, obuf, wo, bo, f1w, f1b, f2w, f2b, f3w, f3b, out_logits);
}

// Round 4
// 977.451 us; speedup vs baseline: 2.7749x; 1.0119x over previous
//
#include <hip/hip_runtime.h>
#include <math.h>

#define BZ 256
#define NN 360
#define NP1 361
#define MROWS (BZ*NN)   // 92160
#define POOLL 252
#define KP 384          // padded K (12 tiles of 32)

typedef __attribute__((ext_vector_type(8))) short bf16x8;
typedef __attribute__((ext_vector_type(4))) float f32x4;

__device__ __forceinline__ float lrelu(float x){ return x > 0.f ? x : 0.2f*x; }

__device__ __forceinline__ ushort f2bf(float f){
    union { float f; uint u; } v; v.f = f;
    uint u = v.u + 0x7FFFu + ((v.u >> 16) & 1u);
    return (ushort)(u >> 16);
}
__device__ __forceinline__ float bf2f(ushort h){
    union { uint u; float f; } v; v.u = ((uint)h) << 16;
    return v.f;
}
__device__ __forceinline__ void split2(float v, ushort& hi, ushort& lo){
    hi = f2bf(v);
    lo = f2bf(v - bf2f(hi));
}

// ---------------- zero small stats area ----------------
__global__ void k_zero(float* p, int n){
    int i = blockIdx.x*blockDim.x + threadIdx.x;
    if (i < n) p[i] = 0.f;
}

// ---------------- rowsum: one wave per row ----------------
__global__ __launch_bounds__(256)
void k_rowsum(const float* __restrict__ m, float* __restrict__ rowsum){
    int wid = (blockIdx.x*blockDim.x + threadIdx.x) >> 6;
    int lane = threadIdx.x & 63;
    if (wid >= MROWS) return;
    const float* p = m + (size_t)wid*NN;
    float s = 0.f;
    for (int j = lane; j < NN; j += 64) s += p[j];
    #pragma unroll
    for (int off = 32; off; off >>= 1) s += __shfl_down(s, off);
    if (lane == 0) rowsum[wid] = s;
}

// ---------------- weight prep: Wt hi/lo [j][k] = split(s[k]*W[k][j]), c[j] = sum_k h[k]*W[k][j] ----------------
__global__ __launch_bounds__(384)
void k_prepw(const float* __restrict__ W, int ncols, int joff,
             const float* __restrict__ s, const float* __restrict__ h,
             ushort* __restrict__ Wth, ushort* __restrict__ Wtl, float* __restrict__ cvec)
{
    int j = blockIdx.x;
    int k = threadIdx.x;      // 0..383
    __shared__ float red[6];
    float wv = 0.f, hv = 0.f, sv = 1.f;
    if (k < NN && j < ncols){
        wv = W[(size_t)k*ncols + j];
        if (s) sv = s[k];
        if (h) hv = h[k];
    }
    ushort hi, lo; split2(wv * sv, hi, lo);
    Wth[(size_t)(joff + j)*KP + k] = hi;
    Wtl[(size_t)(joff + j)*KP + k] = lo;
    float v = hv * wv;
    #pragma unroll
    for (int off = 32; off; off >>= 1) v += __shfl_down(v, off);
    int lane = k & 63, wid = k >> 6;
    if (lane == 0) red[wid] = v;
    __syncthreads();
    if (k == 0) cvec[joff + j] = red[0]+red[1]+red[2]+red[3]+red[4]+red[5];
}

// ---------------- big MFMA GEMM, split-bf16 (3-term) ----------------
template<bool AF32, bool RESID>
__global__ __launch_bounds__(256)
void k_gemm_mfma(const void* __restrict__ Avh, const ushort* __restrict__ Avl,
                 const ushort* __restrict__ Wth, const ushort* __restrict__ Wtl,
                 const float* __restrict__ cvec, const float* __restrict__ bias,
                 const float* __restrict__ rowsum,
                 const float* __restrict__ bns, const float* __restrict__ bnh,
                 ushort* __restrict__ Yhi, ushort* __restrict__ Ylo,
                 float* __restrict__ colsum, float* __restrict__ colsq)
{
    __shared__ ushort Ah[128][40];   // rows padded to 80B -> conflict-free b128
    __shared__ ushort Al[128][40];
    __shared__ ushort Bh[64][40];
    __shared__ ushort Bl[64][40];
    int t = threadIdx.x;
    int w = t >> 6, lane = t & 63;
    int l15 = lane & 15, g = lane >> 4;
    int rowblk = blockIdx.x * 128;
    int colblk = blockIdx.y * 64;

    f32x4 acc[2][4];
    #pragma unroll
    for (int i=0;i<2;i++)
        #pragma unroll
        for (int j=0;j<4;j++)
            #pragma unroll
            for (int e=0;e<4;e++) acc[i][j][e] = 0.f;

    int sr = t >> 1;            // A-stage row 0..127
    int sk = (t & 1) * 16;      // A-stage k offset 0/16
    int bc = t >> 2;            // B-stage col 0..63
    int bk = (t & 3) * 8;       // B-stage k offset

    for (int kt = 0; kt < 12; ++kt){
        int k0 = kt * 32;
        if (AF32){
            const float* A = (const float*)Avh;
            uint ph[8], pl[8];
            #pragma unroll
            for (int c=0;c<4;c++){
                int k = k0 + sk + c*4;
                float4 f = make_float4(0.f,0.f,0.f,0.f);
                if (k < NN) f = *(const float4*)&A[(size_t)(rowblk+sr)*NN + k];
                ushort hx,lx,hy,ly,hz,lz,hw,lw;
                split2(f.x,hx,lx); split2(f.y,hy,ly); split2(f.z,hz,lz); split2(f.w,hw,lw);
                ph[c*2]   = (uint)hx | ((uint)hy<<16);
                ph[c*2+1] = (uint)hz | ((uint)hw<<16);
                pl[c*2]   = (uint)lx | ((uint)ly<<16);
                pl[c*2+1] = (uint)lz | ((uint)lw<<16);
            }
            ((uint4*)&Ah[sr][sk])[0]   = make_uint4(ph[0],ph[1],ph[2],ph[3]);
            ((uint4*)&Ah[sr][sk+8])[0] = make_uint4(ph[4],ph[5],ph[6],ph[7]);
            ((uint4*)&Al[sr][sk])[0]   = make_uint4(pl[0],pl[1],pl[2],pl[3]);
            ((uint4*)&Al[sr][sk+8])[0] = make_uint4(pl[4],pl[5],pl[6],pl[7]);
        } else {
            const ushort* AH = (const ushort*)Avh;
            const size_t base = (size_t)(rowblk+sr)*KP + k0 + sk;
            ((int4*)&Ah[sr][sk])[0]   = *(const int4*)&AH[base];
            ((int4*)&Ah[sr][sk+8])[0] = *(const int4*)&AH[base + 8];
            ((int4*)&Al[sr][sk])[0]   = *(const int4*)&Avl[base];
            ((int4*)&Al[sr][sk+8])[0] = *(const int4*)&Avl[base + 8];
        }
        ((int4*)&Bh[bc][bk])[0] = *(const int4*)&Wth[(size_t)(colblk+bc)*KP + k0 + bk];
        ((int4*)&Bl[bc][bk])[0] = *(const int4*)&Wtl[(size_t)(colblk+bc)*KP + k0 + bk];
        __syncthreads();

        bf16x8 ah0 = *(const bf16x8*)&Ah[32*w + l15][8*g];
        bf16x8 ah1 = *(const bf16x8*)&Ah[32*w + 16 + l15][8*g];
        bf16x8 al0 = *(const bf16x8*)&Al[32*w + l15][8*g];
        bf16x8 al1 = *(const bf16x8*)&Al[32*w + 16 + l15][8*g];
        #pragma unroll
        for (int nj=0;nj<4;nj++){
            bf16x8 bh = *(const bf16x8*)&Bh[16*nj + l15][8*g];
            bf16x8 bl = *(const bf16x8*)&Bl[16*nj + l15][8*g];
            acc[0][nj] = __builtin_amdgcn_mfma_f32_16x16x32_bf16(ah0, bh, acc[0][nj], 0, 0, 0);
            acc[0][nj] = __builtin_amdgcn_mfma_f32_16x16x32_bf16(al0, bh, acc[0][nj], 0, 0, 0);
            acc[0][nj] = __builtin_amdgcn_mfma_f32_16x16x32_bf16(ah0, bl, acc[0][nj], 0, 0, 0);
            acc[1][nj] = __builtin_amdgcn_mfma_f32_16x16x32_bf16(ah1, bh, acc[1][nj], 0, 0, 0);
            acc[1][nj] = __builtin_amdgcn_mfma_f32_16x16x32_bf16(al1, bh, acc[1][nj], 0, 0, 0);
            acc[1][nj] = __builtin_amdgcn_mfma_f32_16x16x32_bf16(ah1, bl, acc[1][nj], 0, 0, 0);
        }
        __syncthreads();
    }

    // epilogue
    const ushort* AHg = (const ushort*)Avh;
    float cs_part[4] = {0,0,0,0}, cq_part[4] = {0,0,0,0};
    #pragma unroll
    for (int mi=0;mi<2;mi++){
        #pragma unroll
        for (int nj=0;nj<4;nj++){
            f32x4 d = acc[mi][nj];
            #pragma unroll
            for (int r=0;r<4;r++){
                int row = rowblk + 32*w + 16*mi + 4*g + r;
                int col = colblk + 16*nj + l15;
                float v = 0.f;
                if (col < NN){
                    float pre = rowsum[row] * (d[r] + cvec[col]) + bias[col];
                    v = lrelu(pre);
                    if (RESID){
                        size_t ai = (size_t)row*KP + col;
                        float ar = bf2f(AHg[ai]) + bf2f(Avl[ai]);
                        v += ar * bns[col] + bnh[col];
                    }
                }
                ushort hi, lo; split2(v, hi, lo);
                Yhi[(size_t)row*KP + col] = hi;
                Ylo[(size_t)row*KP + col] = lo;
                cs_part[nj] += v;
                cq_part[nj] += v*v;
            }
        }
    }
    #pragma unroll
    for (int nj=0;nj<4;nj++){
        cs_part[nj] += __shfl_xor(cs_part[nj], 16); cs_part[nj] += __shfl_xor(cs_part[nj], 32);
        cq_part[nj] += __shfl_xor(cq_part[nj], 16); cq_part[nj] += __shfl_xor(cq_part[nj], 32);
    }
    float* red = (float*)&Ah[0][0];
    if (lane < 16){
        #pragma unroll
        for (int nj=0;nj<4;nj++) red[w*64 + nj*16 + l15] = cs_part[nj];
    }
    __syncthreads();
    if (t < 64 && colblk + t < NN)
        atomicAdd(&colsum[colblk + t], red[t] + red[64+t] + red[128+t] + red[192+t]);
    __syncthreads();
    if (lane < 16){
        #pragma unroll
        for (int nj=0;nj<4;nj++) red[w*64 + nj*16 + l15] = cq_part[nj];
    }
    __syncthreads();
    if (t < 64 && colblk + t < NN)
        atomicAdd(&colsq[colblk + t], red[t] + red[64+t] + red[128+t] + red[192+t]);
}

// ---------------- BN finalize ----------------
__global__ void k_bnfin(const float* __restrict__ colsum, const float* __restrict__ colsq,
                        const float* __restrict__ g, const float* __restrict__ b, int ncols,
                        float* __restrict__ scale, float* __restrict__ shift){
    int j = blockIdx.x*blockDim.x + threadIdx.x;
    if (j >= ncols) return;
    float mu = colsum[j] / (float)MROWS;
    float var = colsq[j] / (float)MROWS - mu*mu;
    float sc = g[j] * rsqrtf(var + 1e-5f);
    scale[j] = sc;
    shift[j] = b[j] - mu*sc;
}

// ---------------- gemm2 ----------------
__global__ __launch_bounds__(256)
void k_gemm2_mfma(const ushort* __restrict__ AH, const ushort* __restrict__ AL,
                  const ushort* __restrict__ Wth, const ushort* __restrict__ Wtl,
                  const float* __restrict__ cvec, const float* __restrict__ b1,
                  const float* __restrict__ scb, const float* __restrict__ rowsum,
                  float* __restrict__ h1buf, float* __restrict__ scbuf)
{
    __shared__ ushort Ah[128][40];
    __shared__ ushort Al[128][40];
    __shared__ ushort Bh[80][40];
    __shared__ ushort Bl[80][40];
    int t = threadIdx.x;
    int w = t >> 6, lane = t & 63;
    int l15 = lane & 15, g = lane >> 4;
    int rowblk = blockIdx.x * 128;

    f32x4 acc[2][5];
    #pragma unroll
    for (int i=0;i<2;i++)
        #pragma unroll
        for (int j=0;j<5;j++)
            #pragma unroll
            for (int e=0;e<4;e++) acc[i][j][e] = 0.f;

    int sr = t >> 1, sk = (t & 1) * 16;

    for (int kt = 0; kt < 12; ++kt){
        int k0 = kt * 32;
        {
            const size_t base = (size_t)(rowblk+sr)*KP + k0 + sk;
            ((int4*)&Ah[sr][sk])[0]   = *(const int4*)&AH[base];
            ((int4*)&Ah[sr][sk+8])[0] = *(const int4*)&AH[base + 8];
            ((int4*)&Al[sr][sk])[0]   = *(const int4*)&AL[base];
            ((int4*)&Al[sr][sk+8])[0] = *(const int4*)&AL[base + 8];
        }
        #pragma unroll
        for (int l=0;l<2;l++){
            int c = t + l*256;
            if (c < 320){
                int col = c >> 2, kk = (c & 3)*8;
                ((int4*)&Bh[col][kk])[0] = *(const int4*)&Wth[(size_t)col*KP + k0 + kk];
                ((int4*)&Bl[col][kk])[0] = *(const int4*)&Wtl[(size_t)col*KP + k0 + kk];
            }
        }
        __syncthreads();
        bf16x8 ah0 = *(const bf16x8*)&Ah[32*w + l15][8*g];
        bf16x8 ah1 = *(const bf16x8*)&Ah[32*w + 16 + l15][8*g];
        bf16x8 al0 = *(const bf16x8*)&Al[32*w + l15][8*g];
        bf16x8 al1 = *(const bf16x8*)&Al[32*w + 16 + l15][8*g];
        #pragma unroll
        for (int nj=0;nj<5;nj++){
            bf16x8 bh = *(const bf16x8*)&Bh[16*nj + l15][8*g];
            bf16x8 bl = *(const bf16x8*)&Bl[16*nj + l15][8*g];
            acc[0][nj] = __builtin_amdgcn_mfma_f32_16x16x32_bf16(ah0, bh, acc[0][nj], 0, 0, 0);
            acc[0][nj] = __builtin_amdgcn_mfma_f32_16x16x32_bf16(al0, bh, acc[0][nj], 0, 0, 0);
            acc[0][nj] = __builtin_amdgcn_mfma_f32_16x16x32_bf16(ah0, bl, acc[0][nj], 0, 0, 0);
            acc[1][nj] = __builtin_amdgcn_mfma_f32_16x16x32_bf16(ah1, bh, acc[1][nj], 0, 0, 0);
            acc[1][nj] = __builtin_amdgcn_mfma_f32_16x16x32_bf16(al1, bh, acc[1][nj], 0, 0, 0);
            acc[1][nj] = __builtin_amdgcn_mfma_f32_16x16x32_bf16(ah1, bl, acc[1][nj], 0, 0, 0);
        }
        __syncthreads();
    }

    #pragma unroll
    for (int mi=0;mi<2;mi++){
        #pragma unroll
        for (int nj=0;nj<5;nj++){
            f32x4 d = acc[mi][nj];
            #pragma unroll
            for (int r=0;r<4;r++){
                int row = rowblk + 32*w + 16*mi + 4*g + r;
                int col = 16*nj + l15;
                if (nj < 4){
                    float pre = rowsum[row] * (d[r] + cvec[col]) + b1[col];
                    h1buf[(size_t)row*64 + col] = lrelu(pre);
                } else {
                    int cc = col - 64;
                    float pre = d[r] + cvec[col] + scb[cc];
                    scbuf[(size_t)row*16 + cc] = lrelu(pre);
                }
            }
        }
    }
}

// ---------------- stage2 ----------------
__global__ __launch_bounds__(256)
void k_stage2(const float* __restrict__ h1buf, const float* __restrict__ scbuf,
              const float* __restrict__ w2, const float* __restrict__ b2,
              float* __restrict__ x2, float* __restrict__ colsum, float* __restrict__ colsq)
{
    __shared__ float Hs[64][65];
    __shared__ float Ws[64][17];
    __shared__ float red[16][16];
    int t = threadIdx.x;
    int rowblk = blockIdx.x * 64;
    #pragma unroll
    for (int l=0;l<4;l++){
        int idx = t + l*256;
        Ws[idx>>4][idx&15] = w2[idx];
    }
    #pragma unroll
    for (int l=0;l<16;l++){
        int idx = t + l*256;
        Hs[idx>>6][idx&63] = h1buf[(size_t)rowblk*64 + idx];
    }
    __syncthreads();
    int col = t & 15, rb = t >> 4;
    float ps=0.f, pq=0.f;
    #pragma unroll
    for (int gg=0; gg<4; gg++){
        int r = rb + gg*16;
        float s = b2[col];
        #pragma unroll
        for (int c=0;c<64;c++) s += Hs[r][c]*Ws[c][col];
        float v = lrelu(s) + scbuf[(size_t)(rowblk+r)*16 + col];
        x2[(size_t)(rowblk+r)*16 + col] = v;
        ps += v; pq += v*v;
    }
    red[rb][col] = ps; __syncthreads();
    if (t < 16){
        float s=0.f;
        for (int g=0; g<16; g++) s += red[g][t];
        atomicAdd(&colsum[t], s);
    }
    __syncthreads();
    red[rb][col] = pq; __syncthreads();
    if (t < 16){
        float s=0.f;
        for (int g=0; g<16; g++) s += red[g][t];
        atomicAdd(&colsq[t], s);
    }
}

// ---------------- attention: one block per (batch, head), in-block QKV, 2 rows/wave-iter ----------------
__global__ __launch_bounds__(256)
void k_attn(const float* __restrict__ x2, const float* __restrict__ s2, const float* __restrict__ h2,
            const float* __restrict__ cls,
            const float* __restrict__ wq, const float* __restrict__ bq,
            const float* __restrict__ wk, const float* __restrict__ bk,
            const float* __restrict__ wv, const float* __restrict__ bv,
            float* __restrict__ attn, float* __restrict__ obuf)
{
    int bh = blockIdx.x;
    int b = bh >> 2, h = bh & 3;
    __shared__ float qs[NP1][8];
    __shared__ float ks[NP1][8];
    __shared__ float vs[NP1][8];
    int t = threadIdx.x;

    // QKV phase: 3*361 tasks; each computes 8 head-h outputs for one row of one tensor
    for (int task = t; task < 3*NP1; task += 256){
        int tensor = (task < NP1) ? 0 : ((task < 2*NP1) ? 1 : 2);
        int r = task - tensor*NP1;
        float x[16];
        if (r == 0){
            #pragma unroll
            for (int c=0;c<16;c++) x[c] = cls[c];
        } else {
            const float4* xr = (const float4*)&x2[((size_t)b*NN + (r-1))*16];
            #pragma unroll
            for (int c4=0;c4<4;c4++){
                float4 f = xr[c4];
                x[c4*4+0] = f.x*s2[c4*4+0] + h2[c4*4+0];
                x[c4*4+1] = f.y*s2[c4*4+1] + h2[c4*4+1];
                x[c4*4+2] = f.z*s2[c4*4+2] + h2[c4*4+2];
                x[c4*4+3] = f.w*s2[c4*4+3] + h2[c4*4+3];
            }
        }
        const float* W  = (tensor==0) ? wq : ((tensor==1) ? wk : wv);
        const float* Bb = (tensor==0) ? bq : ((tensor==1) ? bk : bv);
        float* dst = (tensor==0) ? &qs[r][0] : ((tensor==1) ? &ks[r][0] : &vs[r][0]);
        #pragma unroll
        for (int d=0;d<8;d++){
            float a = Bb[h*8+d];
            #pragma unroll
            for (int c=0;c<16;c++) a += x[c]*W[c*32 + h*8 + d];
            dst[d] = a;
        }
    }
    __syncthreads();

    int w = t >> 6, lane = t & 63;
    const float scale = 0.35355339059327373f;
    for (int j2 = 0; j2 < 46; j2++){
        int qi0 = (w<<1) + (j2<<3);
        if (qi0 >= NP1) break;
        int qi1 = qi0 + 1;
        bool v1 = (qi1 < NP1);

        float q0[8], q1[8];
        {
            float4 a = *(const float4*)&qs[qi0][0];
            float4 c = *(const float4*)&qs[qi0][4];
            q0[0]=a.x;q0[1]=a.y;q0[2]=a.z;q0[3]=a.w;q0[4]=c.x;q0[5]=c.y;q0[6]=c.z;q0[7]=c.w;
            int qz = v1 ? qi1 : qi0;
            float4 a1 = *(const float4*)&qs[qz][0];
            float4 c1 = *(const float4*)&qs[qz][4];
            q1[0]=a1.x;q1[1]=a1.y;q1[2]=a1.z;q1[3]=a1.w;q1[4]=c1.x;q1[5]=c1.y;q1[6]=c1.z;q1[7]=c1.w;
        }

        float e0[6], e1[6];
        float mx0 = -1e30f, mx1 = -1e30f;
        #pragma unroll
        for (int j=0;j<6;j++){
            int ki = lane + (j<<6);
            float s0 = -1e30f, s1 = -1e30f;
            if (ki < NP1){
                float4 ka = *(const float4*)&ks[ki][0];
                float4 kb = *(const float4*)&ks[ki][4];
                float kk[8] = {ka.x,ka.y,ka.z,ka.w,kb.x,kb.y,kb.z,kb.w};
                s0 = 0.f; s1 = 0.f;
                #pragma unroll
                for (int d=0;d<8;d++){ s0 += q0[d]*kk[d]; s1 += q1[d]*kk[d]; }
                s0 *= scale; s1 *= scale;
            }
            e0[j]=s0; e1[j]=s1;
            mx0 = fmaxf(mx0, s0); mx1 = fmaxf(mx1, s1);
        }
        #pragma unroll
        for (int off=32; off; off>>=1){
            mx0 = fmaxf(mx0, __shfl_xor(mx0, off));
            mx1 = fmaxf(mx1, __shfl_xor(mx1, off));
        }
        float sum0 = 0.f, sum1 = 0.f;
        #pragma unroll
        for (int j=0;j<6;j++){
            int ki = lane + (j<<6);
            float p0 = (ki < NP1) ? __expf(e0[j]-mx0) : 0.f;
            float p1 = (ki < NP1) ? __expf(e1[j]-mx1) : 0.f;
            e0[j]=p0; e1[j]=p1;
            sum0 += p0; sum1 += p1;
        }
        #pragma unroll
        for (int off=32; off; off>>=1){
            sum0 += __shfl_xor(sum0, off);
            sum1 += __shfl_xor(sum1, off);
        }
        float inv0 = 1.f/sum0;
        float inv1 = v1 ? 1.f/sum1 : 0.f;

        size_t base0 = (size_t)bh*NP1*NP1 + (size_t)qi0*NP1;
        float o0[8] = {0,0,0,0,0,0,0,0};
        float o1[8] = {0,0,0,0,0,0,0,0};
        #pragma unroll
        for (int j=0;j<6;j++){
            int ki = lane + (j<<6);
            if (ki < NP1){
                float4 va = *(const float4*)&vs[ki][0];
                float4 vb = *(const float4*)&vs[ki][4];
                float vv[8] = {va.x,va.y,va.z,va.w,vb.x,vb.y,vb.z,vb.w};
                float p0 = e0[j]*inv0;
                attn[base0 + ki] = p0;
                #pragma unroll
                for (int d=0;d<8;d++) o0[d] += p0*vv[d];
                if (v1){
                    float p1 = e1[j]*inv1;
                    attn[base0 + NP1 + ki] = p1;
                    #pragma unroll
                    for (int d=0;d<8;d++) o1[d] += p1*vv[d];
                }
            }
        }
        #pragma unroll
        for (int d=0;d<8;d++){
            #pragma unroll
            for (int off=32; off; off>>=1){
                o0[d] += __shfl_xor(o0[d], off);
                o1[d] += __shfl_xor(o1[d], off);
            }
        }
        if (lane == 0){
            #pragma unroll
            for (int d=0;d<8;d++)
                obuf[((size_t)b*NP1 + qi0)*32 + h*8 + d] = o0[d];
            if (v1){
                #pragma unroll
                for (int d=0;d<8;d++)
                    obuf[((size_t)b*NP1 + qi1)*32 + h*8 + d] = o1[d];
            }
        }
    }
}

// ---------------- score (cls row) + sigmoid ----------------
__global__ void k_score(const float* __restrict__ attn, float* __restrict__ out_sig,
                        float* __restrict__ score_raw){
    int b = blockIdx.x;
    for (int j = threadIdx.x; j < NN; j += blockDim.x){
        float s = 0.f;
        #pragma unroll
        for (int h=0; h<4; h++)
            s += attn[(((size_t)b*4+h)*NP1)*NP1 + 1 + j];
        score_raw[b*NN + j] = s;
        out_sig[b*NN + j] = 1.f/(1.f + __expf(-s));
    }
}

// ---------------- top-k select + softmax pool + MLP head ----------------
__global__ __launch_bounds__(256)
void k_pool(const float* __restrict__ score_raw, const float* __restrict__ obuf,
            const float* __restrict__ wo, const float* __restrict__ bo,
            const float* __restrict__ f1w, const float* __restrict__ f1b,
            const float* __restrict__ f2w, const float* __restrict__ f2b,
            const float* __restrict__ f3w, const float* __restrict__ f3b,
            float* __restrict__ logits)
{
    int b = blockIdx.x;
    __shared__ float sc[NN];
    __shared__ float w[NN];
    __shared__ float red[256];
    __shared__ float pooled32[32];
    __shared__ float p16[16];
    __shared__ float h64[64];
    __shared__ float h32[32];
    int t = threadIdx.x;
    for (int i=t; i<NN; i+=256) sc[i] = score_raw[b*NN+i];
    __syncthreads();
    float mx = -1e30f;
    for (int i=t; i<NN; i+=256) mx = fmaxf(mx, sc[i]);
    red[t] = mx; __syncthreads();
    for (int s=128; s; s>>=1){ if (t<s) red[t]=fmaxf(red[t],red[t+s]); __syncthreads(); }
    mx = red[0];
    __syncthreads();
    float psum = 0.f;
    for (int i=t; i<NN; i+=256){
        float si = sc[i];
        int r = 0;
        for (int j=0;j<NN;j++){
            float sj = sc[j];
            r += (sj > si) || (sj == si && j < i);
        }
        float wi = (r < POOLL) ? __expf(si - mx) : 0.f;
        w[i] = wi;
        psum += wi;
    }
    red[t] = psum; __syncthreads();
    for (int s=128; s; s>>=1){ if (t<s) red[t]+=red[t+s]; __syncthreads(); }
    float inv = 1.f / red[0];
    __syncthreads();
    if (t < 32){
        float s = 0.f;
        for (int i=0;i<NN;i++) s += w[i] * obuf[((size_t)b*NP1 + 1 + i)*32 + t];
        pooled32[t] = s * inv;
    }
    __syncthreads();
    if (t < 16){
        float s = bo[t];
        for (int d=0;d<32;d++) s += pooled32[d]*wo[d*16+t];
        p16[t] = s;
    }
    __syncthreads();
    if (t < 64){
        float s = f1b[t];
        for (int c=0;c<16;c++) s += p16[c]*f1w[c*64+t];
        h64[t] = lrelu(s);
    }
    __syncthreads();
    if (t < 32){
        float s = f2b[t];
        for (int c=0;c<64;c++) s += h64[c]*f2w[c*32+t];
        h32[t] = lrelu(s);
    }
    __syncthreads();
    if (t < 2){
        float s = f3b[t];
        for (int c=0;c<32;c++) s += h32[c]*f3w[c*2+t];
        logits[b*2+t] = s;
    }
}

extern "C" void kernel_launch(void* const* d_in, const int* in_sizes, int n_in,
                              void* d_out, int out_size, void* d_ws, size_t ws_size,
                              hipStream_t stream)
{
    const float* m    = (const float*)d_in[0];
    const float* nf   = (const float*)d_in[1];
    const float* cls  = (const float*)d_in[2];
    const float* g0w  = (const float*)d_in[3];
    const float* g0b  = (const float*)d_in[4];
    const float* g1w  = (const float*)d_in[5];
    const float* g1b  = (const float*)d_in[6];
    const float* g2w1 = (const float*)d_in[7];
    const float* g2b1 = (const float*)d_in[8];
    const float* g2w2 = (const float*)d_in[9];
    const float* g2b2 = (const float*)d_in[10];
    const float* scw  = (const float*)d_in[11];
    const float* scb  = (const float*)d_in[12];
    const float* bn0g = (const float*)d_in[13];
    const float* bn0b = (const float*)d_in[14];
    const float* bn1g = (const float*)d_in[15];
    const float* bn1b = (const float*)d_in[16];
    const float* bn2g = (const float*)d_in[17];
    const float* bn2b = (const float*)d_in[18];
    const float* wq = (const float*)d_in[19];
    const float* bq = (const float*)d_in[20];
    const float* wk = (const float*)d_in[21];
    const float* bk = (const float*)d_in[22];
    const float* wv = (const float*)d_in[23];
    const float* bv = (const float*)d_in[24];
    const float* wo = (const float*)d_in[25];
    const float* bo = (const float*)d_in[26];
    const float* f1w = (const float*)d_in[27];
    const float* f1b = (const float*)d_in[28];
    const float* f2w = (const float*)d_in[29];
    const float* f2b = (const float*)d_in[30];
    const float* f3w = (const float*)d_in[31];
    const float* f3b = (const float*)d_in[32];

    float* out_logits = (float*)d_out;
    float* out_sig = out_logits + 512;
    float* attn = out_sig + (size_t)BZ*NN;

    // big scratch inside the attn output region (dead until k_attn writes it)
    char* base = (char*)attn;
    const size_t szy = (size_t)MROWS * KP * 2;            // bf16 plane
    ushort* y0h = (ushort*)base;
    ushort* y0l = (ushort*)(base + szy);
    ushort* y1h = (ushort*)(base + 2*szy);
    ushort* y1l = (ushort*)(base + 3*szy);
    float*  h1buf = (float*)(base + 4*szy);
    const size_t szh = (size_t)MROWS * 64 * 4;
    float*  scbuf = (float*)(base + 4*szy + szh);
    const size_t szsc = (size_t)MROWS * 16 * 4;
    ushort* Wt0h = (ushort*)(base + 4*szy + szh + szsc);
    ushort* Wt0l = Wt0h + (size_t)KP*KP;
    ushort* Wt1h = Wt0l + (size_t)KP*KP;
    ushort* Wt1l = Wt1h + (size_t)KP*KP;
    ushort* Wt2h = Wt1l + (size_t)KP*KP;
    ushort* Wt2l = Wt2h + (size_t)KP*KP;
    float*  c0  = (float*)(Wt2l + (size_t)KP*KP);
    float*  c1  = c0 + KP;
    float*  c2  = c1 + KP;

    float* ws = (float*)d_ws;
    float* rowsum = ws;                ws += MROWS;
    float* stats  = ws;                ws += 1472;
    float* cs0 = stats, *cq0 = stats+360, *cs1 = stats+720, *cq1 = stats+1080,
         * cs2 = stats+1440, *cq2 = stats+1456;
    float* s0 = ws;  ws += 360;
    float* h0 = ws;  ws += 360;
    float* s1 = ws;  ws += 360;
    float* hh1 = ws; ws += 360;
    float* s2 = ws;  ws += 16;
    float* h2 = ws;  ws += 16;
    float* x2 = ws;       ws += (size_t)MROWS*16;
    float* obuf = ws;     ws += (size_t)BZ*NP1*32;
    float* score_raw = ws; ws += (size_t)BZ*NN;

    k_zero<<<6, 256, 0, stream>>>(stats, 1472);
    k_rowsum<<<MROWS/4, 256, 0, stream>>>(m, rowsum);
    k_prepw<<<KP, KP, 0, stream>>>(g0w, 360, 0, nullptr, nullptr, Wt0h, Wt0l, c0);

    dim3 g1(720, 6);
    k_gemm_mfma<true,false><<<g1, 256, 0, stream>>>(nf, nullptr, Wt0h, Wt0l, c0, g0b, rowsum, nullptr, nullptr, y0h, y0l, cs0, cq0);
    k_bnfin<<<1, 384, 0, stream>>>(cs0, cq0, bn0g, bn0b, 360, s0, h0);
    k_prepw<<<KP, KP, 0, stream>>>(g1w, 360, 0, s0, h0, Wt1h, Wt1l, c1);
    k_gemm_mfma<false,true><<<g1, 256, 0, stream>>>(y0h, y0l, Wt1h, Wt1l, c1, g1b, rowsum, s0, h0, y1h, y1l, cs1, cq1);
    k_bnfin<<<1, 384, 0, stream>>>(cs1, cq1, bn1g, bn1b, 360, s1, hh1);
    k_prepw<<<64, KP, 0, stream>>>(g2w1, 64, 0, s1, hh1, Wt2h, Wt2l, c2);
    k_prepw<<<16, KP, 0, stream>>>(scw, 16, 64, s1, hh1, Wt2h, Wt2l, c2);
    k_gemm2_mfma<<<720, 256, 0, stream>>>(y1h, y1l, Wt2h, Wt2l, c2, g2b1, scb, rowsum, h1buf, scbuf);
    k_stage2<<<1440, 256, 0, stream>>>(h1buf, scbuf, g2w2, g2b2, x2, cs2, cq2);
    k_bnfin<<<1, 64, 0, stream>>>(cs2, cq2, bn2g, bn2b, 16, s2, h2);
    k_attn<<<BZ*4, 256, 0, stream>>>(x2, s2, h2, cls, wq, bq, wk, bk, wv, bv, attn, obuf);
    k_score<<<BZ, 256, 0, stream>>>(attn, out_sig, score_raw);
    k_pool<<<BZ, 256, 0, stream>>>(score_raw, obuf, wo, bo, f1w, f1b, f2w, f2b, f3w, f3b, out_logits);
}

// Round 5
// 946.523 us; speedup vs baseline: 2.8655x; 1.0327x over previous
//
#include <hip/hip_runtime.h>
#include <math.h>

#define BZ 256
#define NN 360
#define NP1 361
#define MROWS (BZ*NN)   // 92160
#define POOLL 252
#define KP 384          // padded K (12 tiles of 32)

typedef __attribute__((ext_vector_type(8))) short bf16x8;
typedef __attribute__((ext_vector_type(4))) float f32x4;

__device__ __forceinline__ float lrelu(float x){ return x > 0.f ? x : 0.2f*x; }

__device__ __forceinline__ ushort f2bf(float f){
    union { float f; uint u; } v; v.f = f;
    uint u = v.u + 0x7FFFu + ((v.u >> 16) & 1u);
    return (ushort)(u >> 16);
}
__device__ __forceinline__ float bf2f(ushort h){
    union { uint u; float f; } v; v.u = ((uint)h) << 16;
    return v.f;
}
__device__ __forceinline__ void split2(float v, ushort& hi, ushort& lo){
    hi = f2bf(v);
    lo = f2bf(v - bf2f(hi));
}

// ---------------- zero small stats area ----------------
__global__ void k_zero(float* p, int n){
    int i = blockIdx.x*blockDim.x + threadIdx.x;
    if (i < n) p[i] = 0.f;
}

// ---------------- rowsum: one wave per row ----------------
__global__ __launch_bounds__(256)
void k_rowsum(const float* __restrict__ m, float* __restrict__ rowsum){
    int wid = (blockIdx.x*blockDim.x + threadIdx.x) >> 6;
    int lane = threadIdx.x & 63;
    if (wid >= MROWS) return;
    const float* p = m + (size_t)wid*NN;
    float s = 0.f;
    for (int j = lane; j < NN; j += 64) s += p[j];
    #pragma unroll
    for (int off = 32; off; off >>= 1) s += __shfl_down(s, off);
    if (lane == 0) rowsum[wid] = s;
}

// ---------------- weight prep ----------------
__global__ __launch_bounds__(384)
void k_prepw(const float* __restrict__ W, int ncols, int joff,
             const float* __restrict__ s, const float* __restrict__ h,
             ushort* __restrict__ Wth, ushort* __restrict__ Wtl, float* __restrict__ cvec)
{
    int j = blockIdx.x;
    int k = threadIdx.x;      // 0..383
    __shared__ float red[6];
    float wv = 0.f, hv = 0.f, sv = 1.f;
    if (k < NN && j < ncols){
        wv = W[(size_t)k*ncols + j];
        if (s) sv = s[k];
        if (h) hv = h[k];
    }
    ushort hi, lo; split2(wv * sv, hi, lo);
    Wth[(size_t)(joff + j)*KP + k] = hi;
    Wtl[(size_t)(joff + j)*KP + k] = lo;
    float v = hv * wv;
    #pragma unroll
    for (int off = 32; off; off >>= 1) v += __shfl_down(v, off);
    int lane = k & 63, wid = k >> 6;
    if (lane == 0) red[wid] = v;
    __syncthreads();
    if (k == 0) cvec[joff + j] = red[0]+red[1]+red[2]+red[3]+red[4]+red[5];
}

// ---------------- big MFMA GEMM, split-bf16 (3-term) ----------------
template<bool AF32, bool RESID>
__global__ __launch_bounds__(256)
void k_gemm_mfma(const void* __restrict__ Avh, const ushort* __restrict__ Avl,
                 const ushort* __restrict__ Wth, const ushort* __restrict__ Wtl,
                 const float* __restrict__ cvec, const float* __restrict__ bias,
                 const float* __restrict__ rowsum,
                 const float* __restrict__ bns, const float* __restrict__ bnh,
                 ushort* __restrict__ Yhi, ushort* __restrict__ Ylo,
                 float* __restrict__ colsum, float* __restrict__ colsq)
{
    __shared__ ushort Ah[128][40];
    __shared__ ushort Al[128][40];
    __shared__ ushort Bh[64][40];
    __shared__ ushort Bl[64][40];
    int t = threadIdx.x;
    int w = t >> 6, lane = t & 63;
    int l15 = lane & 15, g = lane >> 4;
    int rowblk = blockIdx.x * 128;
    int colblk = blockIdx.y * 64;

    f32x4 acc[2][4];
    #pragma unroll
    for (int i=0;i<2;i++)
        #pragma unroll
        for (int j=0;j<4;j++)
            #pragma unroll
            for (int e=0;e<4;e++) acc[i][j][e] = 0.f;

    int sr = t >> 1;
    int sk = (t & 1) * 16;
    int bc = t >> 2;
    int bk = (t & 3) * 8;

    for (int kt = 0; kt < 12; ++kt){
        int k0 = kt * 32;
        if (AF32){
            const float* A = (const float*)Avh;
            uint ph[8], pl[8];
            #pragma unroll
            for (int c=0;c<4;c++){
                int k = k0 + sk + c*4;
                float4 f = make_float4(0.f,0.f,0.f,0.f);
                if (k < NN) f = *(const float4*)&A[(size_t)(rowblk+sr)*NN + k];
                ushort hx,lx,hy,ly,hz,lz,hw,lw;
                split2(f.x,hx,lx); split2(f.y,hy,ly); split2(f.z,hz,lz); split2(f.w,hw,lw);
                ph[c*2]   = (uint)hx | ((uint)hy<<16);
                ph[c*2+1] = (uint)hz | ((uint)hw<<16);
                pl[c*2]   = (uint)lx | ((uint)ly<<16);
                pl[c*2+1] = (uint)lz | ((uint)lw<<16);
            }
            ((uint4*)&Ah[sr][sk])[0]   = make_uint4(ph[0],ph[1],ph[2],ph[3]);
            ((uint4*)&Ah[sr][sk+8])[0] = make_uint4(ph[4],ph[5],ph[6],ph[7]);
            ((uint4*)&Al[sr][sk])[0]   = make_uint4(pl[0],pl[1],pl[2],pl[3]);
            ((uint4*)&Al[sr][sk+8])[0] = make_uint4(pl[4],pl[5],pl[6],pl[7]);
        } else {
            const ushort* AH = (const ushort*)Avh;
            const size_t base = (size_t)(rowblk+sr)*KP + k0 + sk;
            ((int4*)&Ah[sr][sk])[0]   = *(const int4*)&AH[base];
            ((int4*)&Ah[sr][sk+8])[0] = *(const int4*)&AH[base + 8];
            ((int4*)&Al[sr][sk])[0]   = *(const int4*)&Avl[base];
            ((int4*)&Al[sr][sk+8])[0] = *(const int4*)&Avl[base + 8];
        }
        ((int4*)&Bh[bc][bk])[0] = *(const int4*)&Wth[(size_t)(colblk+bc)*KP + k0 + bk];
        ((int4*)&Bl[bc][bk])[0] = *(const int4*)&Wtl[(size_t)(colblk+bc)*KP + k0 + bk];
        __syncthreads();

        bf16x8 ah0 = *(const bf16x8*)&Ah[32*w + l15][8*g];
        bf16x8 ah1 = *(const bf16x8*)&Ah[32*w + 16 + l15][8*g];
        bf16x8 al0 = *(const bf16x8*)&Al[32*w + l15][8*g];
        bf16x8 al1 = *(const bf16x8*)&Al[32*w + 16 + l15][8*g];
        #pragma unroll
        for (int nj=0;nj<4;nj++){
            bf16x8 bh = *(const bf16x8*)&Bh[16*nj + l15][8*g];
            bf16x8 bl = *(const bf16x8*)&Bl[16*nj + l15][8*g];
            acc[0][nj] = __builtin_amdgcn_mfma_f32_16x16x32_bf16(ah0, bh, acc[0][nj], 0, 0, 0);
            acc[0][nj] = __builtin_amdgcn_mfma_f32_16x16x32_bf16(al0, bh, acc[0][nj], 0, 0, 0);
            acc[0][nj] = __builtin_amdgcn_mfma_f32_16x16x32_bf16(ah0, bl, acc[0][nj], 0, 0, 0);
            acc[1][nj] = __builtin_amdgcn_mfma_f32_16x16x32_bf16(ah1, bh, acc[1][nj], 0, 0, 0);
            acc[1][nj] = __builtin_amdgcn_mfma_f32_16x16x32_bf16(al1, bh, acc[1][nj], 0, 0, 0);
            acc[1][nj] = __builtin_amdgcn_mfma_f32_16x16x32_bf16(ah1, bl, acc[1][nj], 0, 0, 0);
        }
        __syncthreads();
    }

    const ushort* AHg = (const ushort*)Avh;
    float cs_part[4] = {0,0,0,0}, cq_part[4] = {0,0,0,0};
    #pragma unroll
    for (int mi=0;mi<2;mi++){
        #pragma unroll
        for (int nj=0;nj<4;nj++){
            f32x4 d = acc[mi][nj];
            #pragma unroll
            for (int r=0;r<4;r++){
                int row = rowblk + 32*w + 16*mi + 4*g + r;
                int col = colblk + 16*nj + l15;
                float v = 0.f;
                if (col < NN){
                    float pre = rowsum[row] * (d[r] + cvec[col]) + bias[col];
                    v = lrelu(pre);
                    if (RESID){
                        size_t ai = (size_t)row*KP + col;
                        float ar = bf2f(AHg[ai]) + bf2f(Avl[ai]);
                        v += ar * bns[col] + bnh[col];
                    }
                }
                ushort hi, lo; split2(v, hi, lo);
                Yhi[(size_t)row*KP + col] = hi;
                Ylo[(size_t)row*KP + col] = lo;
                cs_part[nj] += v;
                cq_part[nj] += v*v;
            }
        }
    }
    #pragma unroll
    for (int nj=0;nj<4;nj++){
        cs_part[nj] += __shfl_xor(cs_part[nj], 16); cs_part[nj] += __shfl_xor(cs_part[nj], 32);
        cq_part[nj] += __shfl_xor(cq_part[nj], 16); cq_part[nj] += __shfl_xor(cq_part[nj], 32);
    }
    float* red = (float*)&Ah[0][0];
    if (lane < 16){
        #pragma unroll
        for (int nj=0;nj<4;nj++) red[w*64 + nj*16 + l15] = cs_part[nj];
    }
    __syncthreads();
    if (t < 64 && colblk + t < NN)
        atomicAdd(&colsum[colblk + t], red[t] + red[64+t] + red[128+t] + red[192+t]);
    __syncthreads();
    if (lane < 16){
        #pragma unroll
        for (int nj=0;nj<4;nj++) red[w*64 + nj*16 + l15] = cq_part[nj];
    }
    __syncthreads();
    if (t < 64 && colblk + t < NN)
        atomicAdd(&colsq[colblk + t], red[t] + red[64+t] + red[128+t] + red[192+t]);
}

// ---------------- BN finalize ----------------
__global__ void k_bnfin(const float* __restrict__ colsum, const float* __restrict__ colsq,
                        const float* __restrict__ g, const float* __restrict__ b, int ncols,
                        float* __restrict__ scale, float* __restrict__ shift){
    int j = blockIdx.x*blockDim.x + threadIdx.x;
    if (j >= ncols) return;
    float mu = colsum[j] / (float)MROWS;
    float var = colsq[j] / (float)MROWS - mu*mu;
    float sc = g[j] * rsqrtf(var + 1e-5f);
    scale[j] = sc;
    shift[j] = b[j] - mu*sc;
}

// ---------------- gemm2 ----------------
__global__ __launch_bounds__(256)
void k_gemm2_mfma(const ushort* __restrict__ AH, const ushort* __restrict__ AL,
                  const ushort* __restrict__ Wth, const ushort* __restrict__ Wtl,
                  const float* __restrict__ cvec, const float* __restrict__ b1,
                  const float* __restrict__ scb, const float* __restrict__ rowsum,
                  float* __restrict__ h1buf, float* __restrict__ scbuf)
{
    __shared__ ushort Ah[128][40];
    __shared__ ushort Al[128][40];
    __shared__ ushort Bh[80][40];
    __shared__ ushort Bl[80][40];
    int t = threadIdx.x;
    int w = t >> 6, lane = t & 63;
    int l15 = lane & 15, g = lane >> 4;
    int rowblk = blockIdx.x * 128;

    f32x4 acc[2][5];
    #pragma unroll
    for (int i=0;i<2;i++)
        #pragma unroll
        for (int j=0;j<5;j++)
            #pragma unroll
            for (int e=0;e<4;e++) acc[i][j][e] = 0.f;

    int sr = t >> 1, sk = (t & 1) * 16;

    for (int kt = 0; kt < 12; ++kt){
        int k0 = kt * 32;
        {
            const size_t base = (size_t)(rowblk+sr)*KP + k0 + sk;
            ((int4*)&Ah[sr][sk])[0]   = *(const int4*)&AH[base];
            ((int4*)&Ah[sr][sk+8])[0] = *(const int4*)&AH[base + 8];
            ((int4*)&Al[sr][sk])[0]   = *(const int4*)&AL[base];
            ((int4*)&Al[sr][sk+8])[0] = *(const int4*)&AL[base + 8];
        }
        #pragma unroll
        for (int l=0;l<2;l++){
            int c = t + l*256;
            if (c < 320){
                int col = c >> 2, kk = (c & 3)*8;
                ((int4*)&Bh[col][kk])[0] = *(const int4*)&Wth[(size_t)col*KP + k0 + kk];
                ((int4*)&Bl[col][kk])[0] = *(const int4*)&Wtl[(size_t)col*KP + k0 + kk];
            }
        }
        __syncthreads();
        bf16x8 ah0 = *(const bf16x8*)&Ah[32*w + l15][8*g];
        bf16x8 ah1 = *(const bf16x8*)&Ah[32*w + 16 + l15][8*g];
        bf16x8 al0 = *(const bf16x8*)&Al[32*w + l15][8*g];
        bf16x8 al1 = *(const bf16x8*)&Al[32*w + 16 + l15][8*g];
        #pragma unroll
        for (int nj=0;nj<5;nj++){
            bf16x8 bh = *(const bf16x8*)&Bh[16*nj + l15][8*g];
            bf16x8 bl = *(const bf16x8*)&Bl[16*nj + l15][8*g];
            acc[0][nj] = __builtin_amdgcn_mfma_f32_16x16x32_bf16(ah0, bh, acc[0][nj], 0, 0, 0);
            acc[0][nj] = __builtin_amdgcn_mfma_f32_16x16x32_bf16(al0, bh, acc[0][nj], 0, 0, 0);
            acc[0][nj] = __builtin_amdgcn_mfma_f32_16x16x32_bf16(ah0, bl, acc[0][nj], 0, 0, 0);
            acc[1][nj] = __builtin_amdgcn_mfma_f32_16x16x32_bf16(ah1, bh, acc[1][nj], 0, 0, 0);
            acc[1][nj] = __builtin_amdgcn_mfma_f32_16x16x32_bf16(al1, bh, acc[1][nj], 0, 0, 0);
            acc[1][nj] = __builtin_amdgcn_mfma_f32_16x16x32_bf16(ah1, bl, acc[1][nj], 0, 0, 0);
        }
        __syncthreads();
    }

    #pragma unroll
    for (int mi=0;mi<2;mi++){
        #pragma unroll
        for (int nj=0;nj<5;nj++){
            f32x4 d = acc[mi][nj];
            #pragma unroll
            for (int r=0;r<4;r++){
                int row = rowblk + 32*w + 16*mi + 4*g + r;
                int col = 16*nj + l15;
                if (nj < 4){
                    float pre = rowsum[row] * (d[r] + cvec[col]) + b1[col];
                    h1buf[(size_t)row*64 + col] = lrelu(pre);
                } else {
                    int cc = col - 64;
                    float pre = d[r] + cvec[col] + scb[cc];
                    scbuf[(size_t)row*16 + cc] = lrelu(pre);
                }
            }
        }
    }
}

// ---------------- stage2 ----------------
__global__ __launch_bounds__(256)
void k_stage2(const float* __restrict__ h1buf, const float* __restrict__ scbuf,
              const float* __restrict__ w2, const float* __restrict__ b2,
              float* __restrict__ x2, float* __restrict__ colsum, float* __restrict__ colsq)
{
    __shared__ float Hs[64][65];
    __shared__ float Ws[64][17];
    __shared__ float red[16][16];
    int t = threadIdx.x;
    int rowblk = blockIdx.x * 64;
    #pragma unroll
    for (int l=0;l<4;l++){
        int idx = t + l*256;
        Ws[idx>>4][idx&15] = w2[idx];
    }
    #pragma unroll
    for (int l=0;l<16;l++){
        int idx = t + l*256;
        Hs[idx>>6][idx&63] = h1buf[(size_t)rowblk*64 + idx];
    }
    __syncthreads();
    int col = t & 15, rb = t >> 4;
    float ps=0.f, pq=0.f;
    #pragma unroll
    for (int gg=0; gg<4; gg++){
        int r = rb + gg*16;
        float s = b2[col];
        #pragma unroll
        for (int c=0;c<64;c++) s += Hs[r][c]*Ws[c][col];
        float v = lrelu(s) + scbuf[(size_t)(rowblk+r)*16 + col];
        x2[(size_t)(rowblk+r)*16 + col] = v;
        ps += v; pq += v*v;
    }
    red[rb][col] = ps; __syncthreads();
    if (t < 16){
        float s=0.f;
        for (int g=0; g<16; g++) s += red[g][t];
        atomicAdd(&colsum[t], s);
    }
    __syncthreads();
    red[rb][col] = pq; __syncthreads();
    if (t < 16){
        float s=0.f;
        for (int g=0; g<16; g++) s += red[g][t];
        atomicAdd(&colsq[t], s);
    }
}

// ---------------- butterfly: reduce o[8] over 64 lanes; every lane returns sum for d=((l&1)<<2)|(l&2)|((l>>2)&1) ----------------
__device__ __forceinline__ float bfly8(float o[8], int lane){
    int b0 = lane & 1, b1 = lane & 2, b2 = lane & 4;
    float n[4];
    #pragma unroll
    for (int j=0;j<4;j++){
        float give = b0 ? o[j] : o[j+4];
        float keep = b0 ? o[j+4] : o[j];
        n[j] = keep + __shfl_xor(give, 1);
    }
    float m2[2];
    #pragma unroll
    for (int j=0;j<2;j++){
        float give = b1 ? n[j] : n[j+2];
        float keep = b1 ? n[j+2] : n[j];
        m2[j] = keep + __shfl_xor(give, 2);
    }
    float give = b2 ? m2[0] : m2[1];
    float keep = b2 ? m2[1] : m2[0];
    float v = keep + __shfl_xor(give, 4);
    v += __shfl_xor(v, 8);
    v += __shfl_xor(v, 16);
    v += __shfl_xor(v, 32);
    return v;
}

// ---------------- attention: block = (bh, chunk); K/V in float4 LDS; butterfly PV reduce ----------------
__global__ __launch_bounds__(256)
void k_attn(const float* __restrict__ x2, const float* __restrict__ s2, const float* __restrict__ h2,
            const float* __restrict__ cls,
            const float* __restrict__ wq, const float* __restrict__ bq,
            const float* __restrict__ wk, const float* __restrict__ bk,
            const float* __restrict__ wv, const float* __restrict__ bv,
            float* __restrict__ attn, float* __restrict__ obuf)
{
    int blk = blockIdx.x;
    int chunk = blk & 1;
    int bh = blk >> 1;
    int b = bh >> 2, h = bh & 3;
    __shared__ float4 KV[4][NP1];   // [kA(d0-3), kB(d4-7), vA, vB][row]
    int t = threadIdx.x;

    // ---- stage K,V (computed from x_in on the fly) ----
    for (int task = t; task < NP1*16; task += 256){
        int r = task >> 4;
        int sub = task & 15;
        int tensor = sub >> 3;           // 0=K, 1=V
        int d = sub & 7;
        float x[16];
        if (r == 0){
            #pragma unroll
            for (int c=0;c<16;c++) x[c] = cls[c];
        } else {
            const float4* xr = (const float4*)&x2[((size_t)b*NN + (r-1))*16];
            #pragma unroll
            for (int c4=0;c4<4;c4++){
                float4 f = xr[c4];
                x[c4*4+0] = f.x*s2[c4*4+0] + h2[c4*4+0];
                x[c4*4+1] = f.y*s2[c4*4+1] + h2[c4*4+1];
                x[c4*4+2] = f.z*s2[c4*4+2] + h2[c4*4+2];
                x[c4*4+3] = f.w*s2[c4*4+3] + h2[c4*4+3];
            }
        }
        const float* W  = tensor ? wv : wk;
        const float* Bb = tensor ? bv : bk;
        float a = Bb[h*8+d];
        #pragma unroll
        for (int c=0;c<16;c++) a += x[c]*W[c*32 + h*8 + d];
        ((float*)&KV[tensor*2 + (d>>2)][r])[d&3] = a;
    }
    __syncthreads();

    int w = t >> 6, lane = t & 63;
    int row_half = lane >> 5;
    int l5 = lane & 31;
    int qd = l5 & 7, qkc = (l5 >> 3);
    int cbase = chunk * 181;
    int cend  = chunk ? NP1 : 181;

    for (int qi0 = cbase + (w<<1); qi0 < cend; qi0 += 8){
        int qi1 = qi0 + 1;
        bool v1 = (qi1 < cend);

        // --- q for both rows: 32 lanes/row, then broadcast; scale + bias folded ---
        int myrow = row_half ? (v1 ? qi1 : qi0) : qi0;
        float part = 0.f;
        {
            float xv[4];
            if (myrow == 0){
                #pragma unroll
                for (int c=0;c<4;c++) xv[c] = cls[qkc*4+c];
            } else {
                float4 f = *(const float4*)&x2[((size_t)b*NN + (myrow-1))*16 + qkc*4];
                xv[0] = f.x*s2[qkc*4+0] + h2[qkc*4+0];
                xv[1] = f.y*s2[qkc*4+1] + h2[qkc*4+1];
                xv[2] = f.z*s2[qkc*4+2] + h2[qkc*4+2];
                xv[3] = f.w*s2[qkc*4+3] + h2[qkc*4+3];
            }
            #pragma unroll
            for (int c=0;c<4;c++)
                part += xv[c] * wq[(qkc*4+c)*32 + h*8 + qd];
        }
        part += __shfl_xor(part, 8);
        part += __shfl_xor(part, 16);
        part = (part + bq[h*8+qd]) * 0.35355339059327373f;
        float q0[8], q1[8];
        #pragma unroll
        for (int d=0;d<8;d++){ q0[d] = __shfl(part, d); q1[d] = __shfl(part, 32+d); }

        // --- QK^T ---
        float e0[6], e1[6];
        float mx0 = -1e30f, mx1 = -1e30f;
        #pragma unroll
        for (int j=0;j<6;j++){
            int ki = lane + (j<<6);
            int kc = ki > 360 ? 360 : ki;
            float4 ka = KV[0][kc];
            float4 kb = KV[1][kc];
            float s0 = q0[0]*ka.x + q0[1]*ka.y + q0[2]*ka.z + q0[3]*ka.w
                     + q0[4]*kb.x + q0[5]*kb.y + q0[6]*kb.z + q0[7]*kb.w;
            float s1 = q1[0]*ka.x + q1[1]*ka.y + q1[2]*ka.z + q1[3]*ka.w
                     + q1[4]*kb.x + q1[5]*kb.y + q1[6]*kb.z + q1[7]*kb.w;
            if (ki >= NP1){ s0 = -1e30f; s1 = -1e30f; }
            e0[j] = s0; e1[j] = s1;
            mx0 = fmaxf(mx0, s0); mx1 = fmaxf(mx1, s1);
        }
        #pragma unroll
        for (int off=32; off; off>>=1){
            mx0 = fmaxf(mx0, __shfl_xor(mx0, off));
            mx1 = fmaxf(mx1, __shfl_xor(mx1, off));
        }
        float sum0 = 0.f, sum1 = 0.f;
        #pragma unroll
        for (int j=0;j<6;j++){
            float p0 = __expf(e0[j]-mx0);
            float p1 = __expf(e1[j]-mx1);
            e0[j]=p0; e1[j]=p1;
            sum0 += p0; sum1 += p1;
        }
        #pragma unroll
        for (int off=32; off; off>>=1){
            sum0 += __shfl_xor(sum0, off);
            sum1 += __shfl_xor(sum1, off);
        }
        float inv0 = 1.f/sum0;
        float inv1 = 1.f/sum1;

        // --- PV + attn store ---
        size_t abase = (size_t)bh*NP1*NP1 + (size_t)qi0*NP1;
        float o0[8] = {0,0,0,0,0,0,0,0};
        float o1[8] = {0,0,0,0,0,0,0,0};
        #pragma unroll
        for (int j=0;j<6;j++){
            int ki = lane + (j<<6);
            int kc = ki > 360 ? 360 : ki;
            float4 va = KV[2][kc];
            float4 vb = KV[3][kc];
            float p0 = e0[j]*inv0;
            float p1 = e1[j]*inv1;
            if (ki >= NP1){ p0 = 0.f; p1 = 0.f; }
            else {
                attn[abase + ki] = p0;
                if (v1) attn[abase + NP1 + ki] = p1;
            }
            o0[0] += p0*va.x; o0[1] += p0*va.y; o0[2] += p0*va.z; o0[3] += p0*va.w;
            o0[4] += p0*vb.x; o0[5] += p0*vb.y; o0[6] += p0*vb.z; o0[7] += p0*vb.w;
            o1[0] += p1*va.x; o1[1] += p1*va.y; o1[2] += p1*va.z; o1[3] += p1*va.w;
            o1[4] += p1*vb.x; o1[5] += p1*vb.y; o1[6] += p1*vb.z; o1[7] += p1*vb.w;
        }
        float val0 = bfly8(o0, lane);
        float val1 = bfly8(o1, lane);
        int l7 = lane & 7;
        int dmap = ((l7&1)<<2) | (l7&2) | ((l7>>2)&1);
        if (lane < 8)
            obuf[((size_t)b*NP1 + qi0)*32 + h*8 + dmap] = val0;
        else if (lane < 16 && v1)
            obuf[((size_t)b*NP1 + qi1)*32 + h*8 + dmap] = val1;
    }
}

// ---------------- score (cls row) + sigmoid ----------------
__global__ void k_score(const float* __restrict__ attn, float* __restrict__ out_sig,
                        float* __restrict__ score_raw){
    int b = blockIdx.x;
    for (int j = threadIdx.x; j < NN; j += blockDim.x){
        float s = 0.f;
        #pragma unroll
        for (int h=0; h<4; h++)
            s += attn[(((size_t)b*4+h)*NP1)*NP1 + 1 + j];
        score_raw[b*NN + j] = s;
        out_sig[b*NN + j] = 1.f/(1.f + __expf(-s));
    }
}

// ---------------- top-k select + softmax pool + MLP head ----------------
__global__ __launch_bounds__(256)
void k_pool(const float* __restrict__ score_raw, const float* __restrict__ obuf,
            const float* __restrict__ wo, const float* __restrict__ bo,
            const float* __restrict__ f1w, const float* __restrict__ f1b,
            const float* __restrict__ f2w, const float* __restrict__ f2b,
            const float* __restrict__ f3w, const float* __restrict__ f3b,
            float* __restrict__ logits)
{
    int b = blockIdx.x;
    __shared__ float sc[NN];
    __shared__ float w[NN];
    __shared__ float red[256];
    __shared__ float pooled32[32];
    __shared__ float p16[16];
    __shared__ float h64[64];
    __shared__ float h32[32];
    int t = threadIdx.x;
    for (int i=t; i<NN; i+=256) sc[i] = score_raw[b*NN+i];
    __syncthreads();
    float mx = -1e30f;
    for (int i=t; i<NN; i+=256) mx = fmaxf(mx, sc[i]);
    red[t] = mx; __syncthreads();
    for (int s=128; s; s>>=1){ if (t<s) red[t]=fmaxf(red[t],red[t+s]); __syncthreads(); }
    mx = red[0];
    __syncthreads();
    float psum = 0.f;
    for (int i=t; i<NN; i+=256){
        float si = sc[i];
        int r = 0;
        for (int j=0;j<NN;j++){
            float sj = sc[j];
            r += (sj > si) || (sj == si && j < i);
        }
        float wi = (r < POOLL) ? __expf(si - mx) : 0.f;
        w[i] = wi;
        psum += wi;
    }
    red[t] = psum; __syncthreads();
    for (int s=128; s; s>>=1){ if (t<s) red[t]+=red[t+s]; __syncthreads(); }
    float inv = 1.f / red[0];
    __syncthreads();
    if (t < 32){
        float s = 0.f;
        for (int i=0;i<NN;i++) s += w[i] * obuf[((size_t)b*NP1 + 1 + i)*32 + t];
        pooled32[t] = s * inv;
    }
    __syncthreads();
    if (t < 16){
        float s = bo[t];
        for (int d=0;d<32;d++) s += pooled32[d]*wo[d*16+t];
        p16[t] = s;
    }
    __syncthreads();
    if (t < 64){
        float s = f1b[t];
        for (int c=0;c<16;c++) s += p16[c]*f1w[c*64+t];
        h64[t] = lrelu(s);
    }
    __syncthreads();
    if (t < 32){
        float s = f2b[t];
        for (int c=0;c<64;c++) s += h64[c]*f2w[c*32+t];
        h32[t] = lrelu(s);
    }
    __syncthreads();
    if (t < 2){
        float s = f3b[t];
        for (int c=0;c<32;c++) s += h32[c]*f3w[c*2+t];
        logits[b*2+t] = s;
    }
}

extern "C" void kernel_launch(void* const* d_in, const int* in_sizes, int n_in,
                              void* d_out, int out_size, void* d_ws, size_t ws_size,
                              hipStream_t stream)
{
    const float* m    = (const float*)d_in[0];
    const float* nf   = (const float*)d_in[1];
    const float* cls  = (const float*)d_in[2];
    const float* g0w  = (const float*)d_in[3];
    const float* g0b  = (const float*)d_in[4];
    const float* g1w  = (const float*)d_in[5];
    const float* g1b  = (const float*)d_in[6];
    const float* g2w1 = (const float*)d_in[7];
    const float* g2b1 = (const float*)d_in[8];
    const float* g2w2 = (const float*)d_in[9];
    const float* g2b2 = (const float*)d_in[10];
    const float* scw  = (const float*)d_in[11];
    const float* scb  = (const float*)d_in[12];
    const float* bn0g = (const float*)d_in[13];
    const float* bn0b = (const float*)d_in[14];
    const float* bn1g = (const float*)d_in[15];
    const float* bn1b = (const float*)d_in[16];
    const float* bn2g = (const float*)d_in[17];
    const float* bn2b = (const float*)d_in[18];
    const float* wq = (const float*)d_in[19];
    const float* bq = (const float*)d_in[20];
    const float* wk = (const float*)d_in[21];
    const float* bk = (const float*)d_in[22];
    const float* wv = (const float*)d_in[23];
    const float* bv = (const float*)d_in[24];
    const float* wo = (const float*)d_in[25];
    const float* bo = (const float*)d_in[26];
    const float* f1w = (const float*)d_in[27];
    const float* f1b = (const float*)d_in[28];
    const float* f2w = (const float*)d_in[29];
    const float* f2b = (const float*)d_in[30];
    const float* f3w = (const float*)d_in[31];
    const float* f3b = (const float*)d_in[32];

    float* out_logits = (float*)d_out;
    float* out_sig = out_logits + 512;
    float* attn = out_sig + (size_t)BZ*NN;

    // big scratch inside the attn output region (dead until k_attn writes it)
    char* base = (char*)attn;
    const size_t szy = (size_t)MROWS * KP * 2;            // bf16 plane
    ushort* y0h = (ushort*)base;
    ushort* y0l = (ushort*)(base + szy);
    ushort* y1h = (ushort*)(base + 2*szy);
    ushort* y1l = (ushort*)(base + 3*szy);
    float*  h1buf = (float*)(base + 4*szy);
    const size_t szh = (size_t)MROWS * 64 * 4;
    float*  scbuf = (float*)(base + 4*szy + szh);
    const size_t szsc = (size_t)MROWS * 16 * 4;
    ushort* Wt0h = (ushort*)(base + 4*szy + szh + szsc);
    ushort* Wt0l = Wt0h + (size_t)KP*KP;
    ushort* Wt1h = Wt0l + (size_t)KP*KP;
    ushort* Wt1l = Wt1h + (size_t)KP*KP;
    ushort* Wt2h = Wt1l + (size_t)KP*KP;
    ushort* Wt2l = Wt2h + (size_t)KP*KP;
    float*  c0  = (float*)(Wt2l + (size_t)KP*KP);
    float*  c1  = c0 + KP;
    float*  c2  = c1 + KP;

    float* ws = (float*)d_ws;
    float* rowsum = ws;                ws += MROWS;
    float* stats  = ws;                ws += 1472;
    float* cs0 = stats, *cq0 = stats+360, *cs1 = stats+720, *cq1 = stats+1080,
         * cs2 = stats+1440, *cq2 = stats+1456;
    float* s0 = ws;  ws += 360;
    float* h0 = ws;  ws += 360;
    float* s1 = ws;  ws += 360;
    float* hh1 = ws; ws += 360;
    float* s2 = ws;  ws += 16;
    float* h2 = ws;  ws += 16;
    float* x2 = ws;       ws += (size_t)MROWS*16;
    float* obuf = ws;     ws += (size_t)BZ*NP1*32;
    float* score_raw = ws; ws += (size_t)BZ*NN;

    k_zero<<<6, 256, 0, stream>>>(stats, 1472);
    k_rowsum<<<MROWS/4, 256, 0, stream>>>(m, rowsum);
    k_prepw<<<KP, KP, 0, stream>>>(g0w, 360, 0, nullptr, nullptr, Wt0h, Wt0l, c0);

    dim3 g1(720, 6);
    k_gemm_mfma<true,false><<<g1, 256, 0, stream>>>(nf, nullptr, Wt0h, Wt0l, c0, g0b, rowsum, nullptr, nullptr, y0h, y0l, cs0, cq0);
    k_bnfin<<<1, 384, 0, stream>>>(cs0, cq0, bn0g, bn0b, 360, s0, h0);
    k_prepw<<<KP, KP, 0, stream>>>(g1w, 360, 0, s0, h0, Wt1h, Wt1l, c1);
    k_gemm_mfma<false,true><<<g1, 256, 0, stream>>>(y0h, y0l, Wt1h, Wt1l, c1, g1b, rowsum, s0, h0, y1h, y1l, cs1, cq1);
    k_bnfin<<<1, 384, 0, stream>>>(cs1, cq1, bn1g, bn1b, 360, s1, hh1);
    k_prepw<<<64, KP, 0, stream>>>(g2w1, 64, 0, s1, hh1, Wt2h, Wt2l, c2);
    k_prepw<<<16, KP, 0, stream>>>(scw, 16, 64, s1, hh1, Wt2h, Wt2l, c2);
    k_gemm2_mfma<<<720, 256, 0, stream>>>(y1h, y1l, Wt2h, Wt2l, c2, g2b1, scb, rowsum, h1buf, scbuf);
    k_stage2<<<1440, 256, 0, stream>>>(h1buf, scbuf, g2w2, g2b2, x2, cs2, cq2);
    k_bnfin<<<1, 64, 0, stream>>>(cs2, cq2, bn2g, bn2b, 16, s2, h2);
    k_attn<<<BZ*4*2, 256, 0, stream>>>(x2, s2, h2, cls, wq, bq, wk, bk, wv, bv, attn, obuf);
    k_score<<<BZ, 256, 0, stream>>>(attn, out_sig, score_raw);
    k_pool<<<BZ, 256, 0, stream>>>(score_raw, obuf, wo, bo, f1w, f1b, f2w, f2b, f3w, f3b, out_logits);
}

// Round 6
// 791.581 us; speedup vs baseline: 3.4264x; 1.1957x over previous
//
#include <hip/hip_runtime.h>
#include <math.h>

#define BZ 256
#define NN 360
#define NP1 361
#define MROWS (BZ*NN)   // 92160
#define POOLL 252
#define KP 384          // padded K (12 tiles of 32)

typedef __attribute__((ext_vector_type(8))) short bf16x8;
typedef __attribute__((ext_vector_type(4))) float f32x4;

__device__ __forceinline__ float lrelu(float x){ return x > 0.f ? x : 0.2f*x; }

__device__ __forceinline__ ushort f2bf(float f){
    union { float f; uint u; } v; v.f = f;
    uint u = v.u + 0x7FFFu + ((v.u >> 16) & 1u);
    return (ushort)(u >> 16);
}
__device__ __forceinline__ float bf2f(ushort h){
    union { uint u; float f; } v; v.u = ((uint)h) << 16;
    return v.f;
}
__device__ __forceinline__ void split2(float v, ushort& hi, ushort& lo){
    hi = f2bf(v);
    lo = f2bf(v - bf2f(hi));
}

// ---------------- zero small stats area ----------------
__global__ void k_zero(float* p, int n){
    int i = blockIdx.x*blockDim.x + threadIdx.x;
    if (i < n) p[i] = 0.f;
}

// ---------------- rowsum: one wave per row ----------------
__global__ __launch_bounds__(256)
void k_rowsum(const float* __restrict__ m, float* __restrict__ rowsum){
    int wid = (blockIdx.x*blockDim.x + threadIdx.x) >> 6;
    int lane = threadIdx.x & 63;
    if (wid >= MROWS) return;
    const float* p = m + (size_t)wid*NN;
    float s = 0.f;
    for (int j = lane; j < NN; j += 64) s += p[j];
    #pragma unroll
    for (int off = 32; off; off >>= 1) s += __shfl_down(s, off);
    if (lane == 0) rowsum[wid] = s;
}

// ---------------- weight prep ----------------
__global__ __launch_bounds__(384)
void k_prepw(const float* __restrict__ W, int ncols, int joff,
             const float* __restrict__ s, const float* __restrict__ h,
             ushort* __restrict__ Wth, ushort* __restrict__ Wtl, float* __restrict__ cvec)
{
    int j = blockIdx.x;
    int k = threadIdx.x;      // 0..383
    __shared__ float red[6];
    float wv = 0.f, hv = 0.f, sv = 1.f;
    if (k < NN && j < ncols){
        wv = W[(size_t)k*ncols + j];
        if (s) sv = s[k];
        if (h) hv = h[k];
    }
    ushort hi, lo; split2(wv * sv, hi, lo);
    Wth[(size_t)(joff + j)*KP + k] = hi;
    Wtl[(size_t)(joff + j)*KP + k] = lo;
    float v = hv * wv;
    #pragma unroll
    for (int off = 32; off; off >>= 1) v += __shfl_down(v, off);
    int lane = k & 63, wid = k >> 6;
    if (lane == 0) red[wid] = v;
    __syncthreads();
    if (k == 0) cvec[joff + j] = red[0]+red[1]+red[2]+red[3]+red[4]+red[5];
}

// ---------------- big MFMA GEMM, split-bf16 (3-term), XCD-coherent col-block grouping ----------------
// grid: 4320 blocks 1D. idx = ((gq*6 + jcb) << 3) | gr ; rowblock = gq*8+gr (720 = 90*8), colblock = jcb.
// The 6 col-blocks of a row-block share idx%8 -> same XCD -> A panel L2-reused.
template<bool AF32, bool RESID>
__global__ __launch_bounds__(256)
void k_gemm_mfma(const void* __restrict__ Avh, const ushort* __restrict__ Avl,
                 const ushort* __restrict__ Wth, const ushort* __restrict__ Wtl,
                 const float* __restrict__ cvec, const float* __restrict__ bias,
                 const float* __restrict__ rowsum,
                 const float* __restrict__ bns, const float* __restrict__ bnh,
                 ushort* __restrict__ Yhi, ushort* __restrict__ Ylo,
                 float* __restrict__ colsum, float* __restrict__ colsq)
{
    __shared__ ushort Ah[128][40];
    __shared__ ushort Al[128][40];
    __shared__ ushort Bh[64][40];
    __shared__ ushort Bl[64][40];
    int t = threadIdx.x;
    int w = t >> 6, lane = t & 63;
    int l15 = lane & 15, g = lane >> 4;
    int idx = blockIdx.x;
    int gr = idx & 7;
    int rem = idx >> 3;
    int jcb = rem % 6;
    int gq = rem / 6;
    int rowblk = (gq*8 + gr) * 128;
    int colblk = jcb * 64;

    f32x4 acc[2][4];
    #pragma unroll
    for (int i=0;i<2;i++)
        #pragma unroll
        for (int j=0;j<4;j++)
            #pragma unroll
            for (int e=0;e<4;e++) acc[i][j][e] = 0.f;

    int sr = t >> 1;
    int sk = (t & 1) * 16;
    int bc = t >> 2;
    int bk = (t & 3) * 8;

    for (int kt = 0; kt < 12; ++kt){
        int k0 = kt * 32;
        if (AF32){
            const float* A = (const float*)Avh;
            uint ph[8], pl[8];
            #pragma unroll
            for (int c=0;c<4;c++){
                int k = k0 + sk + c*4;
                float4 f = make_float4(0.f,0.f,0.f,0.f);
                if (k < NN) f = *(const float4*)&A[(size_t)(rowblk+sr)*NN + k];
                ushort hx,lx,hy,ly,hz,lz,hw,lw;
                split2(f.x,hx,lx); split2(f.y,hy,ly); split2(f.z,hz,lz); split2(f.w,hw,lw);
                ph[c*2]   = (uint)hx | ((uint)hy<<16);
                ph[c*2+1] = (uint)hz | ((uint)hw<<16);
                pl[c*2]   = (uint)lx | ((uint)ly<<16);
                pl[c*2+1] = (uint)lz | ((uint)lw<<16);
            }
            ((uint4*)&Ah[sr][sk])[0]   = make_uint4(ph[0],ph[1],ph[2],ph[3]);
            ((uint4*)&Ah[sr][sk+8])[0] = make_uint4(ph[4],ph[5],ph[6],ph[7]);
            ((uint4*)&Al[sr][sk])[0]   = make_uint4(pl[0],pl[1],pl[2],pl[3]);
            ((uint4*)&Al[sr][sk+8])[0] = make_uint4(pl[4],pl[5],pl[6],pl[7]);
        } else {
            const ushort* AH = (const ushort*)Avh;
            const size_t base = (size_t)(rowblk+sr)*KP + k0 + sk;
            ((int4*)&Ah[sr][sk])[0]   = *(const int4*)&AH[base];
            ((int4*)&Ah[sr][sk+8])[0] = *(const int4*)&AH[base + 8];
            ((int4*)&Al[sr][sk])[0]   = *(const int4*)&Avl[base];
            ((int4*)&Al[sr][sk+8])[0] = *(const int4*)&Avl[base + 8];
        }
        ((int4*)&Bh[bc][bk])[0] = *(const int4*)&Wth[(size_t)(colblk+bc)*KP + k0 + bk];
        ((int4*)&Bl[bc][bk])[0] = *(const int4*)&Wtl[(size_t)(colblk+bc)*KP + k0 + bk];
        __syncthreads();

        bf16x8 ah0 = *(const bf16x8*)&Ah[32*w + l15][8*g];
        bf16x8 ah1 = *(const bf16x8*)&Ah[32*w + 16 + l15][8*g];
        bf16x8 al0 = *(const bf16x8*)&Al[32*w + l15][8*g];
        bf16x8 al1 = *(const bf16x8*)&Al[32*w + 16 + l15][8*g];
        #pragma unroll
        for (int nj=0;nj<4;nj++){
            bf16x8 bh = *(const bf16x8*)&Bh[16*nj + l15][8*g];
            bf16x8 bl = *(const bf16x8*)&Bl[16*nj + l15][8*g];
            acc[0][nj] = __builtin_amdgcn_mfma_f32_16x16x32_bf16(ah0, bh, acc[0][nj], 0, 0, 0);
            acc[0][nj] = __builtin_amdgcn_mfma_f32_16x16x32_bf16(al0, bh, acc[0][nj], 0, 0, 0);
            acc[0][nj] = __builtin_amdgcn_mfma_f32_16x16x32_bf16(ah0, bl, acc[0][nj], 0, 0, 0);
            acc[1][nj] = __builtin_amdgcn_mfma_f32_16x16x32_bf16(ah1, bh, acc[1][nj], 0, 0, 0);
            acc[1][nj] = __builtin_amdgcn_mfma_f32_16x16x32_bf16(al1, bh, acc[1][nj], 0, 0, 0);
            acc[1][nj] = __builtin_amdgcn_mfma_f32_16x16x32_bf16(ah1, bl, acc[1][nj], 0, 0, 0);
        }
        __syncthreads();
    }

    const ushort* AHg = (const ushort*)Avh;
    float cs_part[4] = {0,0,0,0}, cq_part[4] = {0,0,0,0};
    #pragma unroll
    for (int mi=0;mi<2;mi++){
        #pragma unroll
        for (int nj=0;nj<4;nj++){
            f32x4 d = acc[mi][nj];
            #pragma unroll
            for (int r=0;r<4;r++){
                int row = rowblk + 32*w + 16*mi + 4*g + r;
                int col = colblk + 16*nj + l15;
                float v = 0.f;
                if (col < NN){
                    float pre = rowsum[row] * (d[r] + cvec[col]) + bias[col];
                    v = lrelu(pre);
                    if (RESID){
                        size_t ai = (size_t)row*KP + col;
                        float ar = bf2f(AHg[ai]) + bf2f(Avl[ai]);
                        v += ar * bns[col] + bnh[col];
                    }
                }
                ushort hi, lo; split2(v, hi, lo);
                Yhi[(size_t)row*KP + col] = hi;
                Ylo[(size_t)row*KP + col] = lo;
                cs_part[nj] += v;
                cq_part[nj] += v*v;
            }
        }
    }
    #pragma unroll
    for (int nj=0;nj<4;nj++){
        cs_part[nj] += __shfl_xor(cs_part[nj], 16); cs_part[nj] += __shfl_xor(cs_part[nj], 32);
        cq_part[nj] += __shfl_xor(cq_part[nj], 16); cq_part[nj] += __shfl_xor(cq_part[nj], 32);
    }
    float* red = (float*)&Ah[0][0];
    if (lane < 16){
        #pragma unroll
        for (int nj=0;nj<4;nj++) red[w*64 + nj*16 + l15] = cs_part[nj];
    }
    __syncthreads();
    if (t < 64 && colblk + t < NN)
        atomicAdd(&colsum[colblk + t], red[t] + red[64+t] + red[128+t] + red[192+t]);
    __syncthreads();
    if (lane < 16){
        #pragma unroll
        for (int nj=0;nj<4;nj++) red[w*64 + nj*16 + l15] = cq_part[nj];
    }
    __syncthreads();
    if (t < 64 && colblk + t < NN)
        atomicAdd(&colsq[colblk + t], red[t] + red[64+t] + red[128+t] + red[192+t]);
}

// ---------------- BN finalize ----------------
__global__ void k_bnfin(const float* __restrict__ colsum, const float* __restrict__ colsq,
                        const float* __restrict__ g, const float* __restrict__ b, int ncols,
                        float* __restrict__ scale, float* __restrict__ shift){
    int j = blockIdx.x*blockDim.x + threadIdx.x;
    if (j >= ncols) return;
    float mu = colsum[j] / (float)MROWS;
    float var = colsq[j] / (float)MROWS - mu*mu;
    float sc = g[j] * rsqrtf(var + 1e-5f);
    scale[j] = sc;
    shift[j] = b[j] - mu*sc;
}

// ---------------- gemm2 ----------------
__global__ __launch_bounds__(256)
void k_gemm2_mfma(const ushort* __restrict__ AH, const ushort* __restrict__ AL,
                  const ushort* __restrict__ Wth, const ushort* __restrict__ Wtl,
                  const float* __restrict__ cvec, const float* __restrict__ b1,
                  const float* __restrict__ scb, const float* __restrict__ rowsum,
                  float* __restrict__ h1buf, float* __restrict__ scbuf)
{
    __shared__ ushort Ah[128][40];
    __shared__ ushort Al[128][40];
    __shared__ ushort Bh[80][40];
    __shared__ ushort Bl[80][40];
    int t = threadIdx.x;
    int w = t >> 6, lane = t & 63;
    int l15 = lane & 15, g = lane >> 4;
    int rowblk = blockIdx.x * 128;

    f32x4 acc[2][5];
    #pragma unroll
    for (int i=0;i<2;i++)
        #pragma unroll
        for (int j=0;j<5;j++)
            #pragma unroll
            for (int e=0;e<4;e++) acc[i][j][e] = 0.f;

    int sr = t >> 1, sk = (t & 1) * 16;

    for (int kt = 0; kt < 12; ++kt){
        int k0 = kt * 32;
        {
            const size_t base = (size_t)(rowblk+sr)*KP + k0 + sk;
            ((int4*)&Ah[sr][sk])[0]   = *(const int4*)&AH[base];
            ((int4*)&Ah[sr][sk+8])[0] = *(const int4*)&AH[base + 8];
            ((int4*)&Al[sr][sk])[0]   = *(const int4*)&AL[base];
            ((int4*)&Al[sr][sk+8])[0] = *(const int4*)&AL[base + 8];
        }
        #pragma unroll
        for (int l=0;l<2;l++){
            int c = t + l*256;
            if (c < 320){
                int col = c >> 2, kk = (c & 3)*8;
                ((int4*)&Bh[col][kk])[0] = *(const int4*)&Wth[(size_t)col*KP + k0 + kk];
                ((int4*)&Bl[col][kk])[0] = *(const int4*)&Wtl[(size_t)col*KP + k0 + kk];
            }
        }
        __syncthreads();
        bf16x8 ah0 = *(const bf16x8*)&Ah[32*w + l15][8*g];
        bf16x8 ah1 = *(const bf16x8*)&Ah[32*w + 16 + l15][8*g];
        bf16x8 al0 = *(const bf16x8*)&Al[32*w + l15][8*g];
        bf16x8 al1 = *(const bf16x8*)&Al[32*w + 16 + l15][8*g];
        #pragma unroll
        for (int nj=0;nj<5;nj++){
            bf16x8 bh = *(const bf16x8*)&Bh[16*nj + l15][8*g];
            bf16x8 bl = *(const bf16x8*)&Bl[16*nj + l15][8*g];
            acc[0][nj] = __builtin_amdgcn_mfma_f32_16x16x32_bf16(ah0, bh, acc[0][nj], 0, 0, 0);
            acc[0][nj] = __builtin_amdgcn_mfma_f32_16x16x32_bf16(al0, bh, acc[0][nj], 0, 0, 0);
            acc[0][nj] = __builtin_amdgcn_mfma_f32_16x16x32_bf16(ah0, bl, acc[0][nj], 0, 0, 0);
            acc[1][nj] = __builtin_amdgcn_mfma_f32_16x16x32_bf16(ah1, bh, acc[1][nj], 0, 0, 0);
            acc[1][nj] = __builtin_amdgcn_mfma_f32_16x16x32_bf16(al1, bh, acc[1][nj], 0, 0, 0);
            acc[1][nj] = __builtin_amdgcn_mfma_f32_16x16x32_bf16(ah1, bl, acc[1][nj], 0, 0, 0);
        }
        __syncthreads();
    }

    #pragma unroll
    for (int mi=0;mi<2;mi++){
        #pragma unroll
        for (int nj=0;nj<5;nj++){
            f32x4 d = acc[mi][nj];
            #pragma unroll
            for (int r=0;r<4;r++){
                int row = rowblk + 32*w + 16*mi + 4*g + r;
                int col = 16*nj + l15;
                if (nj < 4){
                    float pre = rowsum[row] * (d[r] + cvec[col]) + b1[col];
                    h1buf[(size_t)row*64 + col] = lrelu(pre);
                } else {
                    int cc = col - 64;
                    float pre = d[r] + cvec[col] + scb[cc];
                    scbuf[(size_t)row*16 + cc] = lrelu(pre);
                }
            }
        }
    }
}

// ---------------- stage2 ----------------
__global__ __launch_bounds__(256)
void k_stage2(const float* __restrict__ h1buf, const float* __restrict__ scbuf,
              const float* __restrict__ w2, const float* __restrict__ b2,
              float* __restrict__ x2, float* __restrict__ colsum, float* __restrict__ colsq)
{
    __shared__ float Hs[64][65];
    __shared__ float Ws[64][17];
    __shared__ float red[16][16];
    int t = threadIdx.x;
    int rowblk = blockIdx.x * 64;
    #pragma unroll
    for (int l=0;l<4;l++){
        int idx = t + l*256;
        Ws[idx>>4][idx&15] = w2[idx];
    }
    #pragma unroll
    for (int l=0;l<16;l++){
        int idx = t + l*256;
        Hs[idx>>6][idx&63] = h1buf[(size_t)rowblk*64 + idx];
    }
    __syncthreads();
    int col = t & 15, rb = t >> 4;
    float ps=0.f, pq=0.f;
    #pragma unroll
    for (int gg=0; gg<4; gg++){
        int r = rb + gg*16;
        float s = b2[col];
        #pragma unroll
        for (int c=0;c<64;c++) s += Hs[r][c]*Ws[c][col];
        float v = lrelu(s) + scbuf[(size_t)(rowblk+r)*16 + col];
        x2[(size_t)(rowblk+r)*16 + col] = v;
        ps += v; pq += v*v;
    }
    red[rb][col] = ps; __syncthreads();
    if (t < 16){
        float s=0.f;
        for (int g=0; g<16; g++) s += red[g][t];
        atomicAdd(&colsum[t], s);
    }
    __syncthreads();
    red[rb][col] = pq; __syncthreads();
    if (t < 16){
        float s=0.f;
        for (int g=0; g<16; g++) s += red[g][t];
        atomicAdd(&colsq[t], s);
    }
}

// ---------------- butterfly: reduce o[8] over 64 lanes; lane<8 returns sum for d=((l&1)<<2)|(l&2)|((l>>2)&1) ----------------
__device__ __forceinline__ float bfly8(float o[8], int lane){
    int b0 = lane & 1, b1 = lane & 2, b2 = lane & 4;
    float n[4];
    #pragma unroll
    for (int j=0;j<4;j++){
        float give = b0 ? o[j] : o[j+4];
        float keep = b0 ? o[j+4] : o[j];
        n[j] = keep + __shfl_xor(give, 1);
    }
    float m2[2];
    #pragma unroll
    for (int j=0;j<2;j++){
        float give = b1 ? n[j] : n[j+2];
        float keep = b1 ? n[j+2] : n[j];
        m2[j] = keep + __shfl_xor(give, 2);
    }
    float give = b2 ? m2[0] : m2[1];
    float keep = b2 ? m2[1] : m2[0];
    float v = keep + __shfl_xor(give, 4);
    v += __shfl_xor(v, 8);
    v += __shfl_xor(v, 16);
    v += __shfl_xor(v, 32);
    return v;
}

// ---------------- attention: K/V hoisted to registers per wave; no LDS reads in the q-loop ----------------
__global__ __launch_bounds__(256)
void k_attn(const float* __restrict__ x2, const float* __restrict__ s2, const float* __restrict__ h2,
            const float* __restrict__ cls,
            const float* __restrict__ wq, const float* __restrict__ bq,
            const float* __restrict__ wk, const float* __restrict__ bk,
            const float* __restrict__ wv, const float* __restrict__ bv,
            float* __restrict__ attn, float* __restrict__ obuf)
{
    int blk = blockIdx.x;
    int chunk = blk & 1;
    int bh = blk >> 1;
    int b = bh >> 2, h = bh & 3;
    __shared__ float4 KV[4][NP1];   // [kA(d0-3), kB(d4-7), vA, vB][row]
    int t = threadIdx.x;

    // ---- stage K,V (computed from x_in on the fly) ----
    for (int task = t; task < NP1*16; task += 256){
        int r = task >> 4;
        int sub = task & 15;
        int tensor = sub >> 3;           // 0=K, 1=V
        int d = sub & 7;
        float x[16];
        if (r == 0){
            #pragma unroll
            for (int c=0;c<16;c++) x[c] = cls[c];
        } else {
            const float4* xr = (const float4*)&x2[((size_t)b*NN + (r-1))*16];
            #pragma unroll
            for (int c4=0;c4<4;c4++){
                float4 f = xr[c4];
                x[c4*4+0] = f.x*s2[c4*4+0] + h2[c4*4+0];
                x[c4*4+1] = f.y*s2[c4*4+1] + h2[c4*4+1];
                x[c4*4+2] = f.z*s2[c4*4+2] + h2[c4*4+2];
                x[c4*4+3] = f.w*s2[c4*4+3] + h2[c4*4+3];
            }
        }
        const float* W  = tensor ? wv : wk;
        const float* Bb = tensor ? bv : bk;
        float a = Bb[h*8+d];
        #pragma unroll
        for (int c=0;c<16;c++) a += x[c]*W[c*32 + h*8 + d];
        ((float*)&KV[tensor*2 + (d>>2)][r])[d&3] = a;
    }
    __syncthreads();

    int w = t >> 6, lane = t & 63;
    // ---- hoist this lane's 6 K rows and 6 V rows into registers (fixed for all pairs) ----
    float kreg[6][8], vreg[6][8];
    #pragma unroll
    for (int j=0;j<6;j++){
        int ki = lane + (j<<6);
        int kc = ki > 360 ? 360 : ki;
        float4 ka = KV[0][kc], kb = KV[1][kc];
        float4 va = KV[2][kc], vb = KV[3][kc];
        kreg[j][0]=ka.x; kreg[j][1]=ka.y; kreg[j][2]=ka.z; kreg[j][3]=ka.w;
        kreg[j][4]=kb.x; kreg[j][5]=kb.y; kreg[j][6]=kb.z; kreg[j][7]=kb.w;
        vreg[j][0]=va.x; vreg[j][1]=va.y; vreg[j][2]=va.z; vreg[j][3]=va.w;
        vreg[j][4]=vb.x; vreg[j][5]=vb.y; vreg[j][6]=vb.z; vreg[j][7]=vb.w;
    }

    int row_half = lane >> 5;
    int l5 = lane & 31;
    int qd = l5 & 7, qkc = (l5 >> 3);
    int cbase = chunk * 181;
    int cend  = chunk ? NP1 : 181;

    for (int qi0 = cbase + (w<<1); qi0 < cend; qi0 += 8){
        int qi1 = qi0 + 1;
        bool v1 = (qi1 < cend);

        // --- q for both rows: 32 lanes/row, then broadcast; scale + bias folded ---
        int myrow = row_half ? (v1 ? qi1 : qi0) : qi0;
        float part = 0.f;
        {
            float xv[4];
            if (myrow == 0){
                #pragma unroll
                for (int c=0;c<4;c++) xv[c] = cls[qkc*4+c];
            } else {
                float4 f = *(const float4*)&x2[((size_t)b*NN + (myrow-1))*16 + qkc*4];
                xv[0] = f.x*s2[qkc*4+0] + h2[qkc*4+0];
                xv[1] = f.y*s2[qkc*4+1] + h2[qkc*4+1];
                xv[2] = f.z*s2[qkc*4+2] + h2[qkc*4+2];
                xv[3] = f.w*s2[qkc*4+3] + h2[qkc*4+3];
            }
            #pragma unroll
            for (int c=0;c<4;c++)
                part += xv[c] * wq[(qkc*4+c)*32 + h*8 + qd];
        }
        part += __shfl_xor(part, 8);
        part += __shfl_xor(part, 16);
        part = (part + bq[h*8+qd]) * 0.35355339059327373f;
        float q0[8], q1[8];
        #pragma unroll
        for (int d=0;d<8;d++){ q0[d] = __shfl(part, d); q1[d] = __shfl(part, 32+d); }

        // --- QK^T (registers only) ---
        float e0[6], e1[6];
        float mx0 = -1e30f, mx1 = -1e30f;
        #pragma unroll
        for (int j=0;j<6;j++){
            int ki = lane + (j<<6);
            float s0 = 0.f, s1 = 0.f;
            #pragma unroll
            for (int d=0;d<8;d++){ s0 += q0[d]*kreg[j][d]; s1 += q1[d]*kreg[j][d]; }
            if (ki >= NP1){ s0 = -1e30f; s1 = -1e30f; }
            e0[j] = s0; e1[j] = s1;
            mx0 = fmaxf(mx0, s0); mx1 = fmaxf(mx1, s1);
        }
        #pragma unroll
        for (int off=32; off; off>>=1){
            mx0 = fmaxf(mx0, __shfl_xor(mx0, off));
            mx1 = fmaxf(mx1, __shfl_xor(mx1, off));
        }
        float sum0 = 0.f, sum1 = 0.f;
        #pragma unroll
        for (int j=0;j<6;j++){
            float p0 = __expf(e0[j]-mx0);
            float p1 = __expf(e1[j]-mx1);
            e0[j]=p0; e1[j]=p1;
            sum0 += p0; sum1 += p1;
        }
        #pragma unroll
        for (int off=32; off; off>>=1){
            sum0 += __shfl_xor(sum0, off);
            sum1 += __shfl_xor(sum1, off);
        }
        float inv0 = 1.f/sum0;
        float inv1 = 1.f/sum1;

        // --- PV + attn store (registers only) ---
        size_t abase = (size_t)bh*NP1*NP1 + (size_t)qi0*NP1;
        float o0[8] = {0,0,0,0,0,0,0,0};
        float o1[8] = {0,0,0,0,0,0,0,0};
        #pragma unroll
        for (int j=0;j<6;j++){
            int ki = lane + (j<<6);
            float p0 = e0[j]*inv0;   // 0 for masked tail (e=exp(-inf)=0)
            float p1 = e1[j]*inv1;
            if (ki < NP1){
                attn[abase + ki] = p0;
                if (v1) attn[abase + NP1 + ki] = p1;
            }
            #pragma unroll
            for (int d=0;d<8;d++){
                o0[d] += p0*vreg[j][d];
                o1[d] += p1*vreg[j][d];
            }
        }
        float val0 = bfly8(o0, lane);
        float val1 = bfly8(o1, lane);
        int l7 = lane & 7;
        int dmap = ((l7&1)<<2) | (l7&2) | ((l7>>2)&1);
        if (lane < 8)
            obuf[((size_t)b*NP1 + qi0)*32 + h*8 + dmap] = val0;
        else if (lane < 16 && v1)
            obuf[((size_t)b*NP1 + qi1)*32 + h*8 + dmap] = val1;
    }
}

// ---------------- score (cls row) + sigmoid ----------------
__global__ void k_score(const float* __restrict__ attn, float* __restrict__ out_sig,
                        float* __restrict__ score_raw){
    int b = blockIdx.x;
    for (int j = threadIdx.x; j < NN; j += blockDim.x){
        float s = 0.f;
        #pragma unroll
        for (int h=0; h<4; h++)
            s += attn[(((size_t)b*4+h)*NP1)*NP1 + 1 + j];
        score_raw[b*NN + j] = s;
        out_sig[b*NN + j] = 1.f/(1.f + __expf(-s));
    }
}

// ---------------- top-k select + softmax pool + MLP head ----------------
__global__ __launch_bounds__(256)
void k_pool(const float* __restrict__ score_raw, const float* __restrict__ obuf,
            const float* __restrict__ wo, const float* __restrict__ bo,
            const float* __restrict__ f1w, const float* __restrict__ f1b,
            const float* __restrict__ f2w, const float* __restrict__ f2b,
            const float* __restrict__ f3w, const float* __restrict__ f3b,
            float* __restrict__ logits)
{
    int b = blockIdx.x;
    __shared__ float sc[NN];
    __shared__ float w[NN];
    __shared__ float red[256];
    __shared__ float pooled32[32];
    __shared__ float p16[16];
    __shared__ float h64[64];
    __shared__ float h32[32];
    int t = threadIdx.x;
    for (int i=t; i<NN; i+=256) sc[i] = score_raw[b*NN+i];
    __syncthreads();
    float mx = -1e30f;
    for (int i=t; i<NN; i+=256) mx = fmaxf(mx, sc[i]);
    red[t] = mx; __syncthreads();
    for (int s=128; s; s>>=1){ if (t<s) red[t]=fmaxf(red[t],red[t+s]); __syncthreads(); }
    mx = red[0];
    __syncthreads();
    float psum = 0.f;
    for (int i=t; i<NN; i+=256){
        float si = sc[i];
        int r = 0;
        for (int j=0;j<NN;j++){
            float sj = sc[j];
            r += (sj > si) || (sj == si && j < i);
        }
        float wi = (r < POOLL) ? __expf(si - mx) : 0.f;
        w[i] = wi;
        psum += wi;
    }
    red[t] = psum; __syncthreads();
    for (int s=128; s; s>>=1){ if (t<s) red[t]+=red[t+s]; __syncthreads(); }
    float inv = 1.f / red[0];
    __syncthreads();
    if (t < 32){
        float s = 0.f;
        for (int i=0;i<NN;i++) s += w[i] * obuf[((size_t)b*NP1 + 1 + i)*32 + t];
        pooled32[t] = s * inv;
    }
    __syncthreads();
    if (t < 16){
        float s = bo[t];
        for (int d=0;d<32;d++) s += pooled32[d]*wo[d*16+t];
        p16[t] = s;
    }
    __syncthreads();
    if (t < 64){
        float s = f1b[t];
        for (int c=0;c<16;c++) s += p16[c]*f1w[c*64+t];
        h64[t] = lrelu(s);
    }
    __syncthreads();
    if (t < 32){
        float s = f2b[t];
        for (int c=0;c<64;c++) s += h64[c]*f2w[c*32+t];
        h32[t] = lrelu(s);
    }
    __syncthreads();
    if (t < 2){
        float s = f3b[t];
        for (int c=0;c<32;c++) s += h32[c]*f3w[c*2+t];
        logits[b*2+t] = s;
    }
}

extern "C" void kernel_launch(void* const* d_in, const int* in_sizes, int n_in,
                              void* d_out, int out_size, void* d_ws, size_t ws_size,
                              hipStream_t stream)
{
    const float* m    = (const float*)d_in[0];
    const float* nf   = (const float*)d_in[1];
    const float* cls  = (const float*)d_in[2];
    const float* g0w  = (const float*)d_in[3];
    const float* g0b  = (const float*)d_in[4];
    const float* g1w  = (const float*)d_in[5];
    const float* g1b  = (const float*)d_in[6];
    const float* g2w1 = (const float*)d_in[7];
    const float* g2b1 = (const float*)d_in[8];
    const float* g2w2 = (const float*)d_in[9];
    const float* g2b2 = (const float*)d_in[10];
    const float* scw  = (const float*)d_in[11];
    const float* scb  = (const float*)d_in[12];
    const float* bn0g = (const float*)d_in[13];
    const float* bn0b = (const float*)d_in[14];
    const float* bn1g = (const float*)d_in[15];
    const float* bn1b = (const float*)d_in[16];
    const float* bn2g = (const float*)d_in[17];
    const float* bn2b = (const float*)d_in[18];
    const float* wq = (const float*)d_in[19];
    const float* bq = (const float*)d_in[20];
    const float* wk = (const float*)d_in[21];
    const float* bk = (const float*)d_in[22];
    const float* wv = (const float*)d_in[23];
    const float* bv = (const float*)d_in[24];
    const float* wo = (const float*)d_in[25];
    const float* bo = (const float*)d_in[26];
    const float* f1w = (const float*)d_in[27];
    const float* f1b = (const float*)d_in[28];
    const float* f2w = (const float*)d_in[29];
    const float* f2b = (const float*)d_in[30];
    const float* f3w = (const float*)d_in[31];
    const float* f3b = (const float*)d_in[32];

    float* out_logits = (float*)d_out;
    float* out_sig = out_logits + 512;
    float* attn = out_sig + (size_t)BZ*NN;

    // big scratch inside the attn output region (dead until k_attn writes it)
    char* base = (char*)attn;
    const size_t szy = (size_t)MROWS * KP * 2;            // bf16 plane
    ushort* y0h = (ushort*)base;
    ushort* y0l = (ushort*)(base + szy);
    ushort* y1h = (ushort*)(base + 2*szy);
    ushort* y1l = (ushort*)(base + 3*szy);
    float*  h1buf = (float*)(base + 4*szy);
    const size_t szh = (size_t)MROWS * 64 * 4;
    float*  scbuf = (float*)(base + 4*szy + szh);
    const size_t szsc = (size_t)MROWS * 16 * 4;
    ushort* Wt0h = (ushort*)(base + 4*szy + szh + szsc);
    ushort* Wt0l = Wt0h + (size_t)KP*KP;
    ushort* Wt1h = Wt0l + (size_t)KP*KP;
    ushort* Wt1l = Wt1h + (size_t)KP*KP;
    ushort* Wt2h = Wt1l + (size_t)KP*KP;
    ushort* Wt2l = Wt2h + (size_t)KP*KP;
    float*  c0  = (float*)(Wt2l + (size_t)KP*KP);
    float*  c1  = c0 + KP;
    float*  c2  = c1 + KP;

    float* ws = (float*)d_ws;
    float* rowsum = ws;                ws += MROWS;
    float* stats  = ws;                ws += 1472;
    float* cs0 = stats, *cq0 = stats+360, *cs1 = stats+720, *cq1 = stats+1080,
         * cs2 = stats+1440, *cq2 = stats+1456;
    float* s0 = ws;  ws += 360;
    float* h0 = ws;  ws += 360;
    float* s1 = ws;  ws += 360;
    float* hh1 = ws; ws += 360;
    float* s2 = ws;  ws += 16;
    float* h2 = ws;  ws += 16;
    float* x2 = ws;       ws += (size_t)MROWS*16;
    float* obuf = ws;     ws += (size_t)BZ*NP1*32;
    float* score_raw = ws; ws += (size_t)BZ*NN;

    k_zero<<<6, 256, 0, stream>>>(stats, 1472);
    k_rowsum<<<MROWS/4, 256, 0, stream>>>(m, rowsum);
    k_prepw<<<KP, KP, 0, stream>>>(g0w, 360, 0, nullptr, nullptr, Wt0h, Wt0l, c0);

    k_gemm_mfma<true,false><<<4320, 256, 0, stream>>>(nf, nullptr, Wt0h, Wt0l, c0, g0b, rowsum, nullptr, nullptr, y0h, y0l, cs0, cq0);
    k_bnfin<<<1, 384, 0, stream>>>(cs0, cq0, bn0g, bn0b, 360, s0, h0);
    k_prepw<<<KP, KP, 0, stream>>>(g1w, 360, 0, s0, h0, Wt1h, Wt1l, c1);
    k_gemm_mfma<false,true><<<4320, 256, 0, stream>>>(y0h, y0l, Wt1h, Wt1l, c1, g1b, rowsum, s0, h0, y1h, y1l, cs1, cq1);
    k_bnfin<<<1, 384, 0, stream>>>(cs1, cq1, bn1g, bn1b, 360, s1, hh1);
    k_prepw<<<64, KP, 0, stream>>>(g2w1, 64, 0, s1, hh1, Wt2h, Wt2l, c2);
    k_prepw<<<16, KP, 0, stream>>>(scw, 16, 64, s1, hh1, Wt2h, Wt2l, c2);
    k_gemm2_mfma<<<720, 256, 0, stream>>>(y1h, y1l, Wt2h, Wt2l, c2, g2b1, scb, rowsum, h1buf, scbuf);
    k_stage2<<<1440, 256, 0, stream>>>(h1buf, scbuf, g2w2, g2b2, x2, cs2, cq2);
    k_bnfin<<<1, 64, 0, stream>>>(cs2, cq2, bn2g, bn2b, 16, s2, h2);
    k_attn<<<BZ*4*2, 256, 0, stream>>>(x2, s2, h2, cls, wq, bq, wk, bk, wv, bv, attn, obuf);
    k_score<<<BZ, 256, 0, stream>>>(attn, out_sig, score_raw);
    k_pool<<<BZ, 256, 0, stream>>>(score_raw, obuf, wo, bo, f1w, f1b, f2w, f2b, f3w, f3b, out_logits);
}